// Round 6
// baseline (174.139 us; speedup 1.0000x reference)
//
#include <hip/hip_runtime.h>
#include <hip/hip_bf16.h>

// Problem dims (fixed by reference): B=512, Q=64, S=36, D=1024, SIM=256
#define BB 512
#define QQ 64
#define SS 36
#define DD 1024
#define SIM 256

typedef unsigned short u16x8 __attribute__((ext_vector_type(8)));
typedef unsigned short u16x4 __attribute__((ext_vector_type(4)));
typedef __bf16 bf16x8 __attribute__((ext_vector_type(8)));
typedef float f32x4 __attribute__((ext_vector_type(4)));
typedef unsigned short us;

__device__ __forceinline__ us f2bf(float f) {
  unsigned u = __float_as_uint(f);
  u += 0x7FFFu + ((u >> 16) & 1u);   // round-to-nearest-even
  return (us)(u >> 16);
}
__device__ __forceinline__ float bf2f(us h) {
  return __uint_as_float(((unsigned)h) << 16);
}

// ---------------------------------------------------------------------------
// K0: one-shot W (256x1024 f32) -> bf16 row-major copy in ws. L2-resident.
// ---------------------------------------------------------------------------
__global__ __launch_bounds__(256) void k0_w16(const float* __restrict__ W,
                                              us* __restrict__ W16) {
  int i = blockIdx.x * 256 + threadIdx.x;  // 65536 float4s
  float4 v = ((const float4*)W)[i];
  ushort4 p;
  p.x = f2bf(v.x); p.y = f2bf(v.y); p.z = f2bf(v.z); p.w = f2bf(v.w);
  ((ushort4*)W16)[i] = p;
}

// ---------------------------------------------------------------------------
// K1 v3: grid=512 (1 batch/block), block=512 (8 waves -> 16 waves/CU, 4/SIMD),
// register-prefetch pipeline (load ch+1 globals into regs during ch's MFMA).
// Wave split: nt = w>>1 (q-cols nt*16..+16); even waves m-tiles{0,1}, odd
// waves m-tile{2}; odd waves 1,3,5 additionally accumulate G row-blocks 0,1,2
// (reuses staged ctx, zero extra HBM). Epilogue: leaky -> l2norm(Q) ->
// softmax(S) -> probs bf16; G bf16 to ws. LDS 30464B.
// ---------------------------------------------------------------------------
__global__ __launch_bounds__(512, 4) void k1_attn(
    const float* __restrict__ query, const float* __restrict__ context,
    const float* __restrict__ matrix, const int* __restrict__ smoothp,
    us* __restrict__ attnBF, us* __restrict__ Gws) {
  __shared__ __align__(16) char smem1[30464];
  us* qmL = (us*)smem1;                // [64][136]
  us* ctxL = (us*)(smem1 + 17408);     // [48][136]
  float* sc = (float*)smem1;           // [48][68] (aliases qmL after GEMM)

  const int t = threadIdx.x;
  const int bb = blockIdx.x;
  const int lane = t & 63, w = t >> 6;
  const int ml = lane & 15, kg = lane >> 4;
  const int nt = w >> 1;               // n-tile (16 q-cols) per wave pair
  const float smf = (float)smoothp[0];

  // staging slot assignment (fixed per thread):
  //  qm: slots idx = t, t+512  (row=idx>>4, c8=idx&15), 1024 slots total
  //  ctx: slot0 idx=t (rows 0..31), slot1 idx=t+512 (t<256, rows 32..47)
  const int qr0 = t >> 4, qc0 = (t & 15) * 8;
  const int qr1 = (t + 512) >> 4, qc1 = qc0;
  const int cr0 = t >> 4;              // 0..31
  const int cr1 = (t + 512) >> 4;      // 32..47 (t<256)

  float4 pq0a, pq0b, pm0a, pm0b, pq1a, pq1b, pm1a, pm1b;
  float4 pc0a, pc0b, pc1a, pc1b;

#define K1_LOAD(d0)                                                            \
  {                                                                            \
    const float4* gq0 = (const float4*)&query[((size_t)bb * QQ + qr0) * DD + (d0) + qc0]; \
    const float4* gm0 = (const float4*)&matrix[((size_t)bb * QQ + qr0) * DD + (d0) + qc0]; \
    pq0a = gq0[0]; pq0b = gq0[1]; pm0a = gm0[0]; pm0b = gm0[1];                \
    const float4* gq1 = (const float4*)&query[((size_t)bb * QQ + qr1) * DD + (d0) + qc1]; \
    const float4* gm1 = (const float4*)&matrix[((size_t)bb * QQ + qr1) * DD + (d0) + qc1]; \
    pq1a = gq1[0]; pq1b = gq1[1]; pm1a = gm1[0]; pm1b = gm1[1];                \
    pc0a = pc0b = pc1a = pc1b = (float4){0.f, 0.f, 0.f, 0.f};                  \
    if (cr0 < 36) {                                                            \
      const float4* gc = (const float4*)&context[((size_t)bb * SS + cr0) * DD + (d0) + qc0]; \
      pc0a = gc[0]; pc0b = gc[1];                                              \
    }                                                                          \
    if (t < 256 && cr1 < 36) {                                                 \
      const float4* gc = (const float4*)&context[((size_t)bb * SS + cr1) * DD + (d0) + qc1]; \
      pc1a = gc[0]; pc1b = gc[1];                                              \
    }                                                                          \
  }

  f32x4 acc0 = (f32x4){0.f, 0.f, 0.f, 0.f};
  f32x4 acc1 = (f32x4){0.f, 0.f, 0.f, 0.f};
  f32x4 gacc[3];
#pragma unroll
  for (int j = 0; j < 3; ++j) gacc[j] = (f32x4){0.f, 0.f, 0.f, 0.f};

  K1_LOAD(0);
  for (int ch = 0; ch < 8; ++ch) {
    __syncthreads();  // prior MFMA reads of LDS done
    // pack regs -> LDS
    {
      u16x8 pk;
      pk[0] = f2bf(pq0a.x * pm0a.x); pk[1] = f2bf(pq0a.y * pm0a.y);
      pk[2] = f2bf(pq0a.z * pm0a.z); pk[3] = f2bf(pq0a.w * pm0a.w);
      pk[4] = f2bf(pq0b.x * pm0b.x); pk[5] = f2bf(pq0b.y * pm0b.y);
      pk[6] = f2bf(pq0b.z * pm0b.z); pk[7] = f2bf(pq0b.w * pm0b.w);
      *(u16x8*)&qmL[qr0 * 136 + qc0] = pk;
      pk[0] = f2bf(pq1a.x * pm1a.x); pk[1] = f2bf(pq1a.y * pm1a.y);
      pk[2] = f2bf(pq1a.z * pm1a.z); pk[3] = f2bf(pq1a.w * pm1a.w);
      pk[4] = f2bf(pq1b.x * pm1b.x); pk[5] = f2bf(pq1b.y * pm1b.y);
      pk[6] = f2bf(pq1b.z * pm1b.z); pk[7] = f2bf(pq1b.w * pm1b.w);
      *(u16x8*)&qmL[qr1 * 136 + qc1] = pk;
      pk[0] = f2bf(pc0a.x); pk[1] = f2bf(pc0a.y); pk[2] = f2bf(pc0a.z); pk[3] = f2bf(pc0a.w);
      pk[4] = f2bf(pc0b.x); pk[5] = f2bf(pc0b.y); pk[6] = f2bf(pc0b.z); pk[7] = f2bf(pc0b.w);
      *(u16x8*)&ctxL[cr0 * 136 + qc0] = pk;
      if (t < 256) {
        pk[0] = f2bf(pc1a.x); pk[1] = f2bf(pc1a.y); pk[2] = f2bf(pc1a.z); pk[3] = f2bf(pc1a.w);
        pk[4] = f2bf(pc1b.x); pk[5] = f2bf(pc1b.y); pk[6] = f2bf(pc1b.z); pk[7] = f2bf(pc1b.w);
        *(u16x8*)&ctxL[cr1 * 136 + qc1] = pk;
      }
    }
    if (ch < 7) K1_LOAD((ch + 1) * 128);  // prefetch next chunk (hides under MFMA)
    __syncthreads();  // LDS ready
#pragma unroll
    for (int ks = 0; ks < 4; ++ks) {
      const int ko = ks * 32 + kg * 8;
      bf16x8 bq = __builtin_bit_cast(bf16x8, *(const u16x8*)&qmL[(nt * 16 + ml) * 136 + ko]);
      if ((w & 1) == 0) {
        bf16x8 af0 = __builtin_bit_cast(bf16x8, *(const u16x8*)&ctxL[(0 + ml) * 136 + ko]);
        bf16x8 af1 = __builtin_bit_cast(bf16x8, *(const u16x8*)&ctxL[(16 + ml) * 136 + ko]);
        acc0 = __builtin_amdgcn_mfma_f32_16x16x32_bf16(af0, bq, acc0, 0, 0, 0);
        acc1 = __builtin_amdgcn_mfma_f32_16x16x32_bf16(af1, bq, acc1, 0, 0, 0);
      } else {
        bf16x8 af2 = __builtin_bit_cast(bf16x8, *(const u16x8*)&ctxL[(32 + ml) * 136 + ko]);
        acc0 = __builtin_amdgcn_mfma_f32_16x16x32_bf16(af2, bq, acc0, 0, 0, 0);
        if (w < 6) {  // waves 1,3,5 -> G row-block nt (=0,1,2)
          bf16x8 ai = __builtin_bit_cast(bf16x8, *(const u16x8*)&ctxL[(nt * 16 + ml) * 136 + ko]);
#pragma unroll
          for (int j = 0; j < 3; ++j) {
            bf16x8 aj = __builtin_bit_cast(bf16x8, *(const u16x8*)&ctxL[(j * 16 + ml) * 136 + ko]);
            gacc[j] = __builtin_amdgcn_mfma_f32_16x16x32_bf16(ai, aj, gacc[j], 0, 0, 0);
          }
        }
      }
    }
  }
  __syncthreads();  // last MFMA reads done before sc aliases qmL

  // spill G (waves 1,3,5)
  if ((w & 1) && w < 6) {
#pragma unroll
    for (int j = 0; j < 3; ++j)
#pragma unroll
      for (int ii = 0; ii < 4; ++ii)
        Gws[(size_t)bb * 2304 + (nt * 16 + kg * 4 + ii) * 48 + j * 16 + ml] = f2bf(gacc[j][ii]);
  }
  // leaky + spill scores to sc[s][q]
  if ((w & 1) == 0) {
#pragma unroll
    for (int ii = 0; ii < 4; ++ii) {
      float v0 = acc0[ii];
      v0 = v0 > 0.f ? v0 : 0.1f * v0;
      sc[(0 + kg * 4 + ii) * 68 + nt * 16 + ml] = v0;
      float v1 = acc1[ii];
      v1 = v1 > 0.f ? v1 : 0.1f * v1;
      sc[(16 + kg * 4 + ii) * 68 + nt * 16 + ml] = v1;
    }
  } else {
#pragma unroll
    for (int ii = 0; ii < 4; ++ii) {
      float v = acc0[ii];
      v = v > 0.f ? v : 0.1f * v;
      sc[(32 + kg * 4 + ii) * 68 + nt * 16 + ml] = v;
    }
  }
  __syncthreads();

  if (t < 36) {  // l2norm over q per row s
    float ssum = 0.f;
    for (int qi = 0; qi < 64; ++qi) { float v = sc[t * 68 + qi]; ssum = fmaf(v, v, ssum); }
    float rn = 1.f / (sqrtf(ssum) + 1e-8f);
    for (int qi = 0; qi < 64; ++qi) sc[t * 68 + qi] *= rn;
  }
  __syncthreads();

  if (t < 64) {  // softmax over s per column q -> probs bf16 to ws
    float mx = -1e30f;
    for (int s2 = 0; s2 < 36; ++s2) mx = fmaxf(mx, sc[s2 * 68 + t]);
    float sum = 0.f;
    float ev[36];
    for (int s2 = 0; s2 < 36; ++s2) {
      float e = __expf((sc[s2 * 68 + t] - mx) * smf);
      ev[s2] = e;
      sum += e;
    }
    float rs = 1.f / sum;
    size_t base = (size_t)bb * (QQ * SS) + t * SS;
#pragma unroll
    for (int s2 = 0; s2 < 36; s2 += 2) {
      ushort2 p;
      p.x = f2bf(ev[s2] * rs);
      p.y = f2bf(ev[s2 + 1] * rs);
      *(ushort2*)&attnBF[base + s2] = p;
    }
  }
}

// ---------------------------------------------------------------------------
// K2 (unchanged, proven): per-batch, 512 thr, 49.7KB LDS.
// init: P16 (probs bf16), G -> V = P.G^T (MFMA) -> rn_q = 1/(sqrt(p.V)+eps)
// per 128-d chunk: stage ctxT[128][76] -> wc = P.C (MFMA) -> A=(q-wc*rn)^2
// bf16 -> sim GEMM accumulate A.W^T. epilogue: +bias, l2norm(256), store.
// ---------------------------------------------------------------------------
template <bool USE_W16>
__global__ __launch_bounds__(512, 4) void k2_fused(
    const float* __restrict__ query, const float* __restrict__ context,
    const float* __restrict__ Wm, const float* __restrict__ bvec,
    const us* __restrict__ attnBF, const us* __restrict__ Gws,
    const us* __restrict__ W16, float* __restrict__ out) {
  __shared__ __align__(16) char smem[49664];
  us* P16s = (us*)smem;                  // [64][72]
  us* ctxTs = (us*)(smem + 9216);        // [128][76], row stride 152B
  us* A16s = (us*)(smem + 28672);        // [64][136]
  us* Gf16L = (us*)(smem + 28672);       // [48][72] (aliases A16s, init only)
  float* biasL = (float*)(smem + 46080); // [256]
  float* rnL = (float*)(smem + 47104);   // [64]
  float* rsum = (float*)(smem + 47360);  // [64*9]

  const int t = threadIdx.x, bb = blockIdx.x;
  const int lane = t & 63, w = t >> 6;
  const int ml = lane & 15, kg = lane >> 4;

  // ---- init: zero pads
  for (int idx = t; idx < 2304; idx += 512) ((unsigned*)P16s)[idx] = 0;
  for (int idx = t; idx < 1728; idx += 512) ((unsigned*)Gf16L)[idx] = 0;
  for (int idx = t; idx < 1792; idx += 512) {  // ctxT cols 36..63 zero (persist)
    int r = idx / 14, c = idx - r * 14;
    *(unsigned*)&ctxTs[r * 76 + 36 + c * 2] = 0;
  }
  if (t < 256) biasL[t] = bvec[t];
  __syncthreads();
  // fill P16 (bf16 copy) and Gf16L
  for (int idx = t; idx < 1152; idx += 512) {
    int q = idx / 18, c2 = idx - q * 18;
    *(unsigned*)&P16s[q * 72 + c2 * 2] = ((const unsigned*)attnBF)[(size_t)bb * 1152 + idx];
  }
  for (int idx = t; idx < 1152; idx += 512) {
    int r = idx / 24, c2 = idx - r * 24;
    *(unsigned*)&Gf16L[r * 72 + c2 * 2] = ((const unsigned*)Gws)[(size_t)bb * 1152 + idx];
  }
  __syncthreads();

  // ---- V = P.G^T (G symmetric), then ||wc_q||^2 = sum_sp p[q][sp]*V[q][sp]
  if (w < 3) {
    f32x4 accv[4];
#pragma unroll
    for (int mt = 0; mt < 4; ++mt) accv[mt] = (f32x4){0.f, 0.f, 0.f, 0.f};
#pragma unroll
    for (int ks = 0; ks < 2; ++ks) {
      const int ko = ks * 32 + kg * 8;
      bf16x8 gfr = __builtin_bit_cast(bf16x8, *(const u16x8*)&Gf16L[(w * 16 + ml) * 72 + ko]);
#pragma unroll
      for (int mt = 0; mt < 4; ++mt) {
        bf16x8 pf = __builtin_bit_cast(bf16x8, *(const u16x8*)&P16s[(mt * 16 + ml) * 72 + ko]);
        accv[mt] = __builtin_amdgcn_mfma_f32_16x16x32_bf16(pf, gfr, accv[mt], 0, 0, 0);
      }
    }
#pragma unroll
    for (int mt = 0; mt < 4; ++mt)
#pragma unroll
      for (int ii = 0; ii < 4; ++ii) {
        int q = mt * 16 + kg * 4 + ii;
        float vv = accv[mt][ii] * bf2f(P16s[q * 72 + w * 16 + ml]);
        vv += __shfl_xor(vv, 1);
        vv += __shfl_xor(vv, 2);
        vv += __shfl_xor(vv, 4);
        vv += __shfl_xor(vv, 8);
        if (ml == 0) rsum[q * 4 + w] = vv;
      }
  }
  __syncthreads();
  if (t < 64) {
    float s2 = rsum[t * 4] + rsum[t * 4 + 1] + rsum[t * 4 + 2];
    rnL[t] = 1.f / (sqrtf(s2) + 1e-8f);
  }

  // ---- main chunk loop
  f32x4 accs[4][2];
#pragma unroll
  for (int mt = 0; mt < 4; ++mt)
#pragma unroll
    for (int ntl = 0; ntl < 2; ++ntl) accs[mt][ntl] = (f32x4){0.f, 0.f, 0.f, 0.f};

  for (int ch = 0; ch < 8; ++ch) {
    const int d0 = ch * 128;
    // (a) stage ctxT: transposed global reads (coalesced rows), b64 LDS writes
    for (int idx = t; idx < 1152; idx += 512) {
      int d = idx & 127, s0 = (idx >> 7) * 4;
      const float* cp = &context[((size_t)bb * SS + s0) * DD + d0 + d];
      u16x4 pk;
      pk[0] = f2bf(cp[0]);
      pk[1] = f2bf(cp[DD]);
      pk[2] = f2bf(cp[2 * DD]);
      pk[3] = f2bf(cp[3 * DD]);
      *(u16x4*)&ctxTs[d * 76 + s0] = pk;
    }
    __syncthreads();  // (b)
    // (c) wc = P.C : wave w owns d-cols [w*16, w*16+16)
    f32x4 aw[4];
#pragma unroll
    for (int mt = 0; mt < 4; ++mt) aw[mt] = (f32x4){0.f, 0.f, 0.f, 0.f};
#pragma unroll
    for (int ks = 0; ks < 2; ++ks) {
      const int ko = ks * 32 + kg * 8;
      u16x4 blo = *(const u16x4*)&ctxTs[(w * 16 + ml) * 76 + ko];
      u16x4 bhi = *(const u16x4*)&ctxTs[(w * 16 + ml) * 76 + ko + 4];
      bf16x8 bfr = __builtin_bit_cast(bf16x8, __builtin_shufflevector(blo, bhi, 0, 1, 2, 3, 4, 5, 6, 7));
#pragma unroll
      for (int mt = 0; mt < 4; ++mt) {
        bf16x8 af = __builtin_bit_cast(bf16x8, *(const u16x8*)&P16s[(mt * 16 + ml) * 72 + ko]);
        aw[mt] = __builtin_amdgcn_mfma_f32_16x16x32_bf16(af, bfr, aw[mt], 0, 0, 0);
      }
    }
    // (d) A = (query - wc*rn)^2 -> A16 bf16
#pragma unroll
    for (int mt = 0; mt < 4; ++mt)
#pragma unroll
      for (int ii = 0; ii < 4; ++ii) {
        int q = mt * 16 + kg * 4 + ii;
        float qv = query[((size_t)bb * QQ + q) * DD + d0 + w * 16 + ml];
        float av = qv - aw[mt][ii] * rnL[q];
        A16s[q * 136 + w * 16 + ml] = f2bf(av * av);
      }
    __syncthreads();  // (e)
    // (f) sim GEMM: wave w owns out cols [w*32, w*32+32)
#pragma unroll
    for (int ks = 0; ks < 4; ++ks) {
      const int ko = ks * 32 + kg * 8;
      bf16x8 bfr[2];
#pragma unroll
      for (int ntl = 0; ntl < 2; ++ntl) {
        const size_t wrow = (size_t)(w * 32 + ntl * 16 + ml);
        if constexpr (USE_W16) {
          bfr[ntl] = __builtin_bit_cast(bf16x8, *(const u16x8*)&W16[wrow * DD + d0 + ko]);
        } else {
          const float4* wp = (const float4*)&Wm[wrow * DD + d0 + ko];
          float4 x = wp[0], y = wp[1];
          u16x8 pk;
          pk[0] = f2bf(x.x); pk[1] = f2bf(x.y); pk[2] = f2bf(x.z); pk[3] = f2bf(x.w);
          pk[4] = f2bf(y.x); pk[5] = f2bf(y.y); pk[6] = f2bf(y.z); pk[7] = f2bf(y.w);
          bfr[ntl] = __builtin_bit_cast(bf16x8, pk);
        }
      }
#pragma unroll
      for (int mt = 0; mt < 4; ++mt) {
        bf16x8 af = __builtin_bit_cast(bf16x8, *(const u16x8*)&A16s[(mt * 16 + ml) * 136 + ko]);
#pragma unroll
        for (int ntl = 0; ntl < 2; ++ntl)
          accs[mt][ntl] = __builtin_amdgcn_mfma_f32_16x16x32_bf16(af, bfr[ntl], accs[mt][ntl], 0, 0, 0);
      }
    }
    __syncthreads();  // (g)
  }

  // ---- epilogue: +bias, l2norm over 256, store
#pragma unroll
  for (int mt = 0; mt < 4; ++mt)
#pragma unroll
    for (int ii = 0; ii < 4; ++ii) {
      int q = mt * 16 + kg * 4 + ii;
      float partial = 0.f;
#pragma unroll
      for (int ntl = 0; ntl < 2; ++ntl) {
        int col = w * 32 + ntl * 16 + ml;
        float v = accs[mt][ntl][ii] + biasL[col];
        partial = fmaf(v, v, partial);
      }
      partial += __shfl_xor(partial, 1);
      partial += __shfl_xor(partial, 2);
      partial += __shfl_xor(partial, 4);
      partial += __shfl_xor(partial, 8);
      if (ml == 0) rsum[q * 9 + w] = partial;
    }
  __syncthreads();
  if (t < 64) {
    float ssum = 0.f;
#pragma unroll
    for (int w2 = 0; w2 < 8; ++w2) ssum += rsum[t * 9 + w2];
    rnL[t] = 1.f / (sqrtf(ssum) + 1e-8f);
  }
  __syncthreads();
#pragma unroll
  for (int mt = 0; mt < 4; ++mt)
#pragma unroll
    for (int ntl = 0; ntl < 2; ++ntl)
#pragma unroll
      for (int ii = 0; ii < 4; ++ii) {
        int q = mt * 16 + kg * 4 + ii;
        int col = w * 32 + ntl * 16 + ml;
        float v = accs[mt][ntl][ii] + biasL[col];
        out[((size_t)bb * QQ + q) * SIM + col] = v * rnL[q];
      }
}

extern "C" void kernel_launch(void* const* d_in, const int* in_sizes, int n_in,
                              void* d_out, int out_size, void* d_ws, size_t ws_size,
                              hipStream_t stream) {
  const float* query = (const float*)d_in[0];
  const float* context = (const float*)d_in[1];
  const float* matrix = (const float*)d_in[2];
  const float* Wm = (const float*)d_in[3];
  const float* bvec = (const float*)d_in[4];
  const int* smoothp = (const int*)d_in[5];
  float* out = (float*)d_out;

  // ws layout: [attn bf16: 2359296][G bf16: 2359296][W16 optional: 524288]
  const size_t attnB = (size_t)BB * QQ * SS * 2;
  us* attnBF = (us*)d_ws;
  us* Gws = (us*)((char*)d_ws + attnB);
  us* W16 = (us*)((char*)d_ws + 2 * attnB);
  const bool useW16 = ws_size >= 2 * attnB + (size_t)SIM * DD * 2;

  k1_attn<<<dim3(BB), dim3(512), 0, stream>>>(query, context, matrix, smoothp, attnBF, Gws);
  if (useW16) {
    k0_w16<<<dim3(SIM * DD / 1024), dim3(256), 0, stream>>>(Wm, W16);
    k2_fused<true><<<dim3(BB), dim3(512), 0, stream>>>(query, context, Wm, bvec, attnBF, Gws, W16, out);
  } else {
    k2_fused<false><<<dim3(BB), dim3(512), 0, stream>>>(query, context, Wm, bvec, attnBF, Gws, W16, out);
  }
}

// Round 7
// 168.755 us; speedup vs baseline: 1.0319x; 1.0319x over previous
//
#include <hip/hip_runtime.h>
#include <hip/hip_bf16.h>

// Problem dims (fixed by reference): B=512, Q=64, S=36, D=1024, SIM=256
#define BB 512
#define QQ 64
#define SS 36
#define DD 1024
#define SIM 256

typedef unsigned short u16x8 __attribute__((ext_vector_type(8)));
typedef unsigned short u16x4 __attribute__((ext_vector_type(4)));
typedef __bf16 bf16x8 __attribute__((ext_vector_type(8)));
typedef float f32x4 __attribute__((ext_vector_type(4)));
typedef unsigned short us;

__device__ __forceinline__ us f2bf(float f) {
  unsigned u = __float_as_uint(f);
  u += 0x7FFFu + ((u >> 16) & 1u);   // round-to-nearest-even
  return (us)(u >> 16);
}
__device__ __forceinline__ float bf2f(us h) {
  return __uint_as_float(((unsigned)h) << 16);
}

// ---------------------------------------------------------------------------
// K0: one-shot W (256x1024 f32) -> bf16 row-major copy in ws. L2-resident.
// ---------------------------------------------------------------------------
__global__ __launch_bounds__(256) void k0_w16(const float* __restrict__ W,
                                              us* __restrict__ W16) {
  int i = blockIdx.x * 256 + threadIdx.x;  // 65536 float4s
  float4 v = ((const float4*)W)[i];
  ushort4 p;
  p.x = f2bf(v.x); p.y = f2bf(v.y); p.z = f2bf(v.z); p.w = f2bf(v.w);
  ((ushort4*)W16)[i] = p;
}

// ---------------------------------------------------------------------------
// K1 v4 = R6 structure + per-block chunk-order swizzle (channel decamping).
// grid=512 (1 batch/block), block=512 (8 waves), register-prefetch pipeline.
// Wave split: nt = w>>1; even waves m-tiles{0,1}, odd waves m-tile{2};
// odd waves 1,3,5 accumulate G row-blocks. Epilogue: leaky -> l2norm(Q) ->
// softmax(S) -> probs bf16; G bf16 to ws. LDS 30464B.
// ---------------------------------------------------------------------------
__global__ __launch_bounds__(512, 4) void k1_attn(
    const float* __restrict__ query, const float* __restrict__ context,
    const float* __restrict__ matrix, const int* __restrict__ smoothp,
    us* __restrict__ attnBF, us* __restrict__ Gws) {
  __shared__ __align__(16) char smem1[30464];
  us* qmL = (us*)smem1;                // [64][136]
  us* ctxL = (us*)(smem1 + 17408);     // [48][136]
  float* sc = (float*)smem1;           // [48][68] (aliases qmL after GEMM)

  const int t = threadIdx.x;
  const int bb = blockIdx.x;
  const int lane = t & 63, w = t >> 6;
  const int ml = lane & 15, kg = lane >> 4;
  const int nt = w >> 1;               // n-tile (16 q-cols) per wave pair
  const float smf = (float)smoothp[0];
  // chunk-order swizzle: decorrelate which 512B stratum of the 4KB rows each
  // block reads at a given instant (anti channel-camping).
  const int chs = ((bb >> 3) ^ bb) & 7;

  const int qr0 = t >> 4, qc0 = (t & 15) * 8;
  const int qr1 = (t + 512) >> 4, qc1 = qc0;
  const int cr0 = t >> 4;              // 0..31
  const int cr1 = (t + 512) >> 4;      // 32..47 (t<256)

  float4 pq0a, pq0b, pm0a, pm0b, pq1a, pq1b, pm1a, pm1b;
  float4 pc0a, pc0b, pc1a, pc1b;

#define K1_LOAD(d0)                                                            \
  {                                                                            \
    const float4* gq0 = (const float4*)&query[((size_t)bb * QQ + qr0) * DD + (d0) + qc0]; \
    const float4* gm0 = (const float4*)&matrix[((size_t)bb * QQ + qr0) * DD + (d0) + qc0]; \
    pq0a = gq0[0]; pq0b = gq0[1]; pm0a = gm0[0]; pm0b = gm0[1];                \
    const float4* gq1 = (const float4*)&query[((size_t)bb * QQ + qr1) * DD + (d0) + qc1]; \
    const float4* gm1 = (const float4*)&matrix[((size_t)bb * QQ + qr1) * DD + (d0) + qc1]; \
    pq1a = gq1[0]; pq1b = gq1[1]; pm1a = gm1[0]; pm1b = gm1[1];                \
    pc0a = pc0b = pc1a = pc1b = (float4){0.f, 0.f, 0.f, 0.f};                  \
    if (cr0 < 36) {                                                            \
      const float4* gc = (const float4*)&context[((size_t)bb * SS + cr0) * DD + (d0) + qc0]; \
      pc0a = gc[0]; pc0b = gc[1];                                              \
    }                                                                          \
    if (t < 256 && cr1 < 36) {                                                 \
      const float4* gc = (const float4*)&context[((size_t)bb * SS + cr1) * DD + (d0) + qc1]; \
      pc1a = gc[0]; pc1b = gc[1];                                              \
    }                                                                          \
  }

  f32x4 acc0 = (f32x4){0.f, 0.f, 0.f, 0.f};
  f32x4 acc1 = (f32x4){0.f, 0.f, 0.f, 0.f};
  f32x4 gacc[3];
#pragma unroll
  for (int j = 0; j < 3; ++j) gacc[j] = (f32x4){0.f, 0.f, 0.f, 0.f};

  K1_LOAD(chs * 128);
  for (int ch = 0; ch < 8; ++ch) {
    __syncthreads();  // prior MFMA reads of LDS done
    // pack regs -> LDS (data for stratum ((ch+chs)&7))
    {
      u16x8 pk;
      pk[0] = f2bf(pq0a.x * pm0a.x); pk[1] = f2bf(pq0a.y * pm0a.y);
      pk[2] = f2bf(pq0a.z * pm0a.z); pk[3] = f2bf(pq0a.w * pm0a.w);
      pk[4] = f2bf(pq0b.x * pm0b.x); pk[5] = f2bf(pq0b.y * pm0b.y);
      pk[6] = f2bf(pq0b.z * pm0b.z); pk[7] = f2bf(pq0b.w * pm0b.w);
      *(u16x8*)&qmL[qr0 * 136 + qc0] = pk;
      pk[0] = f2bf(pq1a.x * pm1a.x); pk[1] = f2bf(pq1a.y * pm1a.y);
      pk[2] = f2bf(pq1a.z * pm1a.z); pk[3] = f2bf(pq1a.w * pm1a.w);
      pk[4] = f2bf(pq1b.x * pm1b.x); pk[5] = f2bf(pq1b.y * pm1b.y);
      pk[6] = f2bf(pq1b.z * pm1b.z); pk[7] = f2bf(pq1b.w * pm1b.w);
      *(u16x8*)&qmL[qr1 * 136 + qc1] = pk;
      pk[0] = f2bf(pc0a.x); pk[1] = f2bf(pc0a.y); pk[2] = f2bf(pc0a.z); pk[3] = f2bf(pc0a.w);
      pk[4] = f2bf(pc0b.x); pk[5] = f2bf(pc0b.y); pk[6] = f2bf(pc0b.z); pk[7] = f2bf(pc0b.w);
      *(u16x8*)&ctxL[cr0 * 136 + qc0] = pk;
      if (t < 256) {
        pk[0] = f2bf(pc1a.x); pk[1] = f2bf(pc1a.y); pk[2] = f2bf(pc1a.z); pk[3] = f2bf(pc1a.w);
        pk[4] = f2bf(pc1b.x); pk[5] = f2bf(pc1b.y); pk[6] = f2bf(pc1b.z); pk[7] = f2bf(pc1b.w);
        *(u16x8*)&ctxL[cr1 * 136 + qc1] = pk;
      }
    }
    if (ch < 7) K1_LOAD((((ch + 1 + chs) & 7) * 128));  // prefetch next stratum
    __syncthreads();  // LDS ready
#pragma unroll
    for (int ks = 0; ks < 4; ++ks) {
      const int ko = ks * 32 + kg * 8;
      bf16x8 bq = __builtin_bit_cast(bf16x8, *(const u16x8*)&qmL[(nt * 16 + ml) * 136 + ko]);
      if ((w & 1) == 0) {
        bf16x8 af0 = __builtin_bit_cast(bf16x8, *(const u16x8*)&ctxL[(0 + ml) * 136 + ko]);
        bf16x8 af1 = __builtin_bit_cast(bf16x8, *(const u16x8*)&ctxL[(16 + ml) * 136 + ko]);
        acc0 = __builtin_amdgcn_mfma_f32_16x16x32_bf16(af0, bq, acc0, 0, 0, 0);
        acc1 = __builtin_amdgcn_mfma_f32_16x16x32_bf16(af1, bq, acc1, 0, 0, 0);
      } else {
        bf16x8 af2 = __builtin_bit_cast(bf16x8, *(const u16x8*)&ctxL[(32 + ml) * 136 + ko]);
        acc0 = __builtin_amdgcn_mfma_f32_16x16x32_bf16(af2, bq, acc0, 0, 0, 0);
        if (w < 6) {  // waves 1,3,5 -> G row-block nt (=0,1,2)
          bf16x8 ai = __builtin_bit_cast(bf16x8, *(const u16x8*)&ctxL[(nt * 16 + ml) * 136 + ko]);
#pragma unroll
          for (int j = 0; j < 3; ++j) {
            bf16x8 aj = __builtin_bit_cast(bf16x8, *(const u16x8*)&ctxL[(j * 16 + ml) * 136 + ko]);
            gacc[j] = __builtin_amdgcn_mfma_f32_16x16x32_bf16(ai, aj, gacc[j], 0, 0, 0);
          }
        }
      }
    }
  }
  __syncthreads();  // last MFMA reads done before sc aliases qmL

  // spill G (waves 1,3,5)
  if ((w & 1) && w < 6) {
#pragma unroll
    for (int j = 0; j < 3; ++j)
#pragma unroll
      for (int ii = 0; ii < 4; ++ii)
        Gws[(size_t)bb * 2304 + (nt * 16 + kg * 4 + ii) * 48 + j * 16 + ml] = f2bf(gacc[j][ii]);
  }
  // leaky + spill scores to sc[s][q]
  if ((w & 1) == 0) {
#pragma unroll
    for (int ii = 0; ii < 4; ++ii) {
      float v0 = acc0[ii];
      v0 = v0 > 0.f ? v0 : 0.1f * v0;
      sc[(0 + kg * 4 + ii) * 68 + nt * 16 + ml] = v0;
      float v1 = acc1[ii];
      v1 = v1 > 0.f ? v1 : 0.1f * v1;
      sc[(16 + kg * 4 + ii) * 68 + nt * 16 + ml] = v1;
    }
  } else {
#pragma unroll
    for (int ii = 0; ii < 4; ++ii) {
      float v = acc0[ii];
      v = v > 0.f ? v : 0.1f * v;
      sc[(32 + kg * 4 + ii) * 68 + nt * 16 + ml] = v;
    }
  }
  __syncthreads();

  if (t < 36) {  // l2norm over q per row s
    float ssum = 0.f;
    for (int qi = 0; qi < 64; ++qi) { float v = sc[t * 68 + qi]; ssum = fmaf(v, v, ssum); }
    float rn = 1.f / (sqrtf(ssum) + 1e-8f);
    for (int qi = 0; qi < 64; ++qi) sc[t * 68 + qi] *= rn;
  }
  __syncthreads();

  if (t < 64) {  // softmax over s per column q -> probs bf16 to ws
    float mx = -1e30f;
    for (int s2 = 0; s2 < 36; ++s2) mx = fmaxf(mx, sc[s2 * 68 + t]);
    float sum = 0.f;
    float ev[36];
    for (int s2 = 0; s2 < 36; ++s2) {
      float e = __expf((sc[s2 * 68 + t] - mx) * smf);
      ev[s2] = e;
      sum += e;
    }
    float rs = 1.f / sum;
    size_t base = (size_t)bb * (QQ * SS) + t * SS;
#pragma unroll
    for (int s2 = 0; s2 < 36; s2 += 2) {
      ushort2 p;
      p.x = f2bf(ev[s2] * rs);
      p.y = f2bf(ev[s2 + 1] * rs);
      *(ushort2*)&attnBF[base + s2] = p;
    }
  }
}

// ---------------------------------------------------------------------------
// K2 = R4 structure + per-block chunk-order swizzle (channel decamping).
// per-batch, 512 thr, 49.7KB LDS.
// ---------------------------------------------------------------------------
template <bool USE_W16>
__global__ __launch_bounds__(512, 4) void k2_fused(
    const float* __restrict__ query, const float* __restrict__ context,
    const float* __restrict__ Wm, const float* __restrict__ bvec,
    const us* __restrict__ attnBF, const us* __restrict__ Gws,
    const us* __restrict__ W16, float* __restrict__ out) {
  __shared__ __align__(16) char smem[49664];
  us* P16s = (us*)smem;                  // [64][72]
  us* ctxTs = (us*)(smem + 9216);        // [128][76], row stride 152B
  us* A16s = (us*)(smem + 28672);        // [64][136]
  us* Gf16L = (us*)(smem + 28672);       // [48][72] (aliases A16s, init only)
  float* biasL = (float*)(smem + 46080); // [256]
  float* rnL = (float*)(smem + 47104);   // [64]
  float* rsum = (float*)(smem + 47360);  // [64*9]

  const int t = threadIdx.x, bb = blockIdx.x;
  const int lane = t & 63, w = t >> 6;
  const int ml = lane & 15, kg = lane >> 4;
  const int chs = ((bb >> 3) ^ bb) & 7;  // chunk-order swizzle

  // ---- init: zero pads
  for (int idx = t; idx < 2304; idx += 512) ((unsigned*)P16s)[idx] = 0;
  for (int idx = t; idx < 1728; idx += 512) ((unsigned*)Gf16L)[idx] = 0;
  for (int idx = t; idx < 1792; idx += 512) {  // ctxT cols 36..63 zero (persist)
    int r = idx / 14, c = idx - r * 14;
    *(unsigned*)&ctxTs[r * 76 + 36 + c * 2] = 0;
  }
  if (t < 256) biasL[t] = bvec[t];
  __syncthreads();
  // fill P16 (bf16 copy) and Gf16L
  for (int idx = t; idx < 1152; idx += 512) {
    int q = idx / 18, c2 = idx - q * 18;
    *(unsigned*)&P16s[q * 72 + c2 * 2] = ((const unsigned*)attnBF)[(size_t)bb * 1152 + idx];
  }
  for (int idx = t; idx < 1152; idx += 512) {
    int r = idx / 24, c2 = idx - r * 24;
    *(unsigned*)&Gf16L[r * 72 + c2 * 2] = ((const unsigned*)Gws)[(size_t)bb * 1152 + idx];
  }
  __syncthreads();

  // ---- V = P.G^T (G symmetric), then ||wc_q||^2 = sum_sp p[q][sp]*V[q][sp]
  if (w < 3) {
    f32x4 accv[4];
#pragma unroll
    for (int mt = 0; mt < 4; ++mt) accv[mt] = (f32x4){0.f, 0.f, 0.f, 0.f};
#pragma unroll
    for (int ks = 0; ks < 2; ++ks) {
      const int ko = ks * 32 + kg * 8;
      bf16x8 gfr = __builtin_bit_cast(bf16x8, *(const u16x8*)&Gf16L[(w * 16 + ml) * 72 + ko]);
#pragma unroll
      for (int mt = 0; mt < 4; ++mt) {
        bf16x8 pf = __builtin_bit_cast(bf16x8, *(const u16x8*)&P16s[(mt * 16 + ml) * 72 + ko]);
        accv[mt] = __builtin_amdgcn_mfma_f32_16x16x32_bf16(pf, gfr, accv[mt], 0, 0, 0);
      }
    }
#pragma unroll
    for (int mt = 0; mt < 4; ++mt)
#pragma unroll
      for (int ii = 0; ii < 4; ++ii) {
        int q = mt * 16 + kg * 4 + ii;
        float vv = accv[mt][ii] * bf2f(P16s[q * 72 + w * 16 + ml]);
        vv += __shfl_xor(vv, 1);
        vv += __shfl_xor(vv, 2);
        vv += __shfl_xor(vv, 4);
        vv += __shfl_xor(vv, 8);
        if (ml == 0) rsum[q * 4 + w] = vv;
      }
  }
  __syncthreads();
  if (t < 64) {
    float s2 = rsum[t * 4] + rsum[t * 4 + 1] + rsum[t * 4 + 2];
    rnL[t] = 1.f / (sqrtf(s2) + 1e-8f);
  }

  // ---- main chunk loop
  f32x4 accs[4][2];
#pragma unroll
  for (int mt = 0; mt < 4; ++mt)
#pragma unroll
    for (int ntl = 0; ntl < 2; ++ntl) accs[mt][ntl] = (f32x4){0.f, 0.f, 0.f, 0.f};

  for (int ch = 0; ch < 8; ++ch) {
    const int d0 = ((ch + chs) & 7) * 128;
    // (a) stage ctxT: transposed global reads (coalesced rows), b64 LDS writes
    for (int idx = t; idx < 1152; idx += 512) {
      int d = idx & 127, s0 = (idx >> 7) * 4;
      const float* cp = &context[((size_t)bb * SS + s0) * DD + d0 + d];
      u16x4 pk;
      pk[0] = f2bf(cp[0]);
      pk[1] = f2bf(cp[DD]);
      pk[2] = f2bf(cp[2 * DD]);
      pk[3] = f2bf(cp[3 * DD]);
      *(u16x4*)&ctxTs[d * 76 + s0] = pk;
    }
    __syncthreads();  // (b)
    // (c) wc = P.C : wave w owns d-cols [w*16, w*16+16)
    f32x4 aw[4];
#pragma unroll
    for (int mt = 0; mt < 4; ++mt) aw[mt] = (f32x4){0.f, 0.f, 0.f, 0.f};
#pragma unroll
    for (int ks = 0; ks < 2; ++ks) {
      const int ko = ks * 32 + kg * 8;
      u16x4 blo = *(const u16x4*)&ctxTs[(w * 16 + ml) * 76 + ko];
      u16x4 bhi = *(const u16x4*)&ctxTs[(w * 16 + ml) * 76 + ko + 4];
      bf16x8 bfr = __builtin_bit_cast(bf16x8, __builtin_shufflevector(blo, bhi, 0, 1, 2, 3, 4, 5, 6, 7));
#pragma unroll
      for (int mt = 0; mt < 4; ++mt) {
        bf16x8 af = __builtin_bit_cast(bf16x8, *(const u16x8*)&P16s[(mt * 16 + ml) * 72 + ko]);
        aw[mt] = __builtin_amdgcn_mfma_f32_16x16x32_bf16(af, bfr, aw[mt], 0, 0, 0);
      }
    }
    // (d) A = (query - wc*rn)^2 -> A16 bf16
#pragma unroll
    for (int mt = 0; mt < 4; ++mt)
#pragma unroll
      for (int ii = 0; ii < 4; ++ii) {
        int q = mt * 16 + kg * 4 + ii;
        float qv = query[((size_t)bb * QQ + q) * DD + d0 + w * 16 + ml];
        float av = qv - aw[mt][ii] * rnL[q];
        A16s[q * 136 + w * 16 + ml] = f2bf(av * av);
      }
    __syncthreads();  // (e)
    // (f) sim GEMM: wave w owns out cols [w*32, w*32+32)
#pragma unroll
    for (int ks = 0; ks < 4; ++ks) {
      const int ko = ks * 32 + kg * 8;
      bf16x8 bfr[2];
#pragma unroll
      for (int ntl = 0; ntl < 2; ++ntl) {
        const size_t wrow = (size_t)(w * 32 + ntl * 16 + ml);
        if constexpr (USE_W16) {
          bfr[ntl] = __builtin_bit_cast(bf16x8, *(const u16x8*)&W16[wrow * DD + d0 + ko]);
        } else {
          const float4* wp = (const float4*)&Wm[wrow * DD + d0 + ko];
          float4 x = wp[0], y = wp[1];
          u16x8 pk;
          pk[0] = f2bf(x.x); pk[1] = f2bf(x.y); pk[2] = f2bf(x.z); pk[3] = f2bf(x.w);
          pk[4] = f2bf(y.x); pk[5] = f2bf(y.y); pk[6] = f2bf(y.z); pk[7] = f2bf(y.w);
          bfr[ntl] = __builtin_bit_cast(bf16x8, pk);
        }
      }
#pragma unroll
      for (int mt = 0; mt < 4; ++mt) {
        bf16x8 af = __builtin_bit_cast(bf16x8, *(const u16x8*)&A16s[(mt * 16 + ml) * 136 + ko]);
#pragma unroll
        for (int ntl = 0; ntl < 2; ++ntl)
          accs[mt][ntl] = __builtin_amdgcn_mfma_f32_16x16x32_bf16(af, bfr[ntl], accs[mt][ntl], 0, 0, 0);
      }
    }
    __syncthreads();  // (g)
  }

  // ---- epilogue: +bias, l2norm over 256, store
#pragma unroll
  for (int mt = 0; mt < 4; ++mt)
#pragma unroll
    for (int ii = 0; ii < 4; ++ii) {
      int q = mt * 16 + kg * 4 + ii;
      float partial = 0.f;
#pragma unroll
      for (int ntl = 0; ntl < 2; ++ntl) {
        int col = w * 32 + ntl * 16 + ml;
        float v = accs[mt][ntl][ii] + biasL[col];
        partial = fmaf(v, v, partial);
      }
      partial += __shfl_xor(partial, 1);
      partial += __shfl_xor(partial, 2);
      partial += __shfl_xor(partial, 4);
      partial += __shfl_xor(partial, 8);
      if (ml == 0) rsum[q * 9 + w] = partial;
    }
  __syncthreads();
  if (t < 64) {
    float ssum = 0.f;
#pragma unroll
    for (int w2 = 0; w2 < 8; ++w2) ssum += rsum[t * 9 + w2];
    rnL[t] = 1.f / (sqrtf(ssum) + 1e-8f);
  }
  __syncthreads();
#pragma unroll
  for (int mt = 0; mt < 4; ++mt)
#pragma unroll
    for (int ntl = 0; ntl < 2; ++ntl)
#pragma unroll
      for (int ii = 0; ii < 4; ++ii) {
        int q = mt * 16 + kg * 4 + ii;
        int col = w * 32 + ntl * 16 + ml;
        float v = accs[mt][ntl][ii] + biasL[col];
        out[((size_t)bb * QQ + q) * SIM + col] = v * rnL[q];
      }
}

extern "C" void kernel_launch(void* const* d_in, const int* in_sizes, int n_in,
                              void* d_out, int out_size, void* d_ws, size_t ws_size,
                              hipStream_t stream) {
  const float* query = (const float*)d_in[0];
  const float* context = (const float*)d_in[1];
  const float* matrix = (const float*)d_in[2];
  const float* Wm = (const float*)d_in[3];
  const float* bvec = (const float*)d_in[4];
  const int* smoothp = (const int*)d_in[5];
  float* out = (float*)d_out;

  // ws layout: [attn bf16: 2359296][G bf16: 2359296][W16 optional: 524288]
  const size_t attnB = (size_t)BB * QQ * SS * 2;
  us* attnBF = (us*)d_ws;
  us* Gws = (us*)((char*)d_ws + attnB);
  us* W16 = (us*)((char*)d_ws + 2 * attnB);
  const bool useW16 = ws_size >= 2 * attnB + (size_t)SIM * DD * 2;

  k1_attn<<<dim3(BB), dim3(512), 0, stream>>>(query, context, matrix, smoothp, attnBF, Gws);
  if (useW16) {
    k0_w16<<<dim3(SIM * DD / 1024), dim3(256), 0, stream>>>(Wm, W16);
    k2_fused<true><<<dim3(BB), dim3(512), 0, stream>>>(query, context, Wm, bvec, attnBF, Gws, W16, out);
  } else {
    k2_fused<false><<<dim3(BB), dim3(512), 0, stream>>>(query, context, Wm, bvec, attnBF, Gws, W16, out);
  }
}

// Round 8
// 167.913 us; speedup vs baseline: 1.0371x; 1.0050x over previous
//
#include <hip/hip_runtime.h>
#include <hip/hip_bf16.h>

// Problem dims (fixed by reference): B=512, Q=64, S=36, D=1024, SIM=256
#define BB 512
#define QQ 64
#define SS 36
#define DD 1024
#define SIM 256

typedef unsigned short u16x8 __attribute__((ext_vector_type(8)));
typedef unsigned short u16x4 __attribute__((ext_vector_type(4)));
typedef __bf16 bf16x8 __attribute__((ext_vector_type(8)));
typedef float f32x4 __attribute__((ext_vector_type(4)));
typedef unsigned short us;

__device__ __forceinline__ us f2bf(float f) {
  unsigned u = __float_as_uint(f);
  u += 0x7FFFu + ((u >> 16) & 1u);   // round-to-nearest-even
  return (us)(u >> 16);
}
__device__ __forceinline__ float bf2f(us h) {
  return __uint_as_float(((unsigned)h) << 16);
}

// ---------------------------------------------------------------------------
// K0: one-shot W (256x1024 f32) -> bf16 row-major copy in ws. L2-resident.
// ---------------------------------------------------------------------------
__global__ __launch_bounds__(256) void k0_w16(const float* __restrict__ W,
                                              us* __restrict__ W16) {
  int i = blockIdx.x * 256 + threadIdx.x;  // 65536 float4s
  float4 v = ((const float4*)W)[i];
  ushort4 p;
  p.x = f2bf(v.x); p.y = f2bf(v.y); p.z = f2bf(v.z); p.w = f2bf(v.w);
  ((ushort4*)W16)[i] = p;
}

// ---------------------------------------------------------------------------
// K1 v5 — barrier-free streaming. grid=512 (1 batch/block), block=256 (4
// waves; wave w owns q-cols w*16..+16). ctx staged in LDS per d-half
// [48][520] bf16 (rows 36-47 zeroed once); query/matrix NEVER staged: each
// wave loads its own MFMA B-fragments straight from global (coalesced 128B
// row segments), packs qm=q*m in regs, MFMAs vs LDS ctx. No barriers inside
// the 16-step stream loop -> loads from all waves overlap continuously.
// Waves 0-2 accumulate G=ctx.ctx^T per half from LDS (zero extra HBM).
// Epilogue: leaky -> l2norm(Q) -> softmax(S) -> probs bf16; G bf16 to ws.
// LDS: ctxL[48][520]@0 (49920B) | sc[48][68] f32 @49920 (13056B) = 62976B.
// 2 blocks/CU, grid exactly resident (512 blocks = 256 CU x 2).
// ---------------------------------------------------------------------------
__global__ __launch_bounds__(256, 2) void k1_attn(
    const float* __restrict__ query, const float* __restrict__ context,
    const float* __restrict__ matrix, const int* __restrict__ smoothp,
    us* __restrict__ attnBF, us* __restrict__ Gws) {
  __shared__ __align__(16) char smem1[62976];
  us* ctxL = (us*)smem1;                  // [48][520] bf16
  float* sc = (float*)(smem1 + 49920);    // [48][68] f32

  const int t = threadIdx.x;
  const int bb = blockIdx.x;
  const int lane = t & 63, w = t >> 6;    // w = n-tile (q-cols w*16..+16)
  const int ml = lane & 15, kg = lane >> 4;
  const float smf = (float)smoothp[0];

  // zero ctx rows 36-47 once (keeps m-tile-2 / G pad rows exact zeros)
  for (int idx = t; idx < 3120; idx += 256)
    ((unsigned*)(ctxL + 36 * 520))[idx] = 0;

  const size_t qmoff = ((size_t)bb * QQ + w * 16 + ml) * DD + kg * 8;
  const float* qrow = query + qmoff;
  const float* mrow = matrix + qmoff;

  f32x4 acc[3];
#pragma unroll
  for (int mt = 0; mt < 3; ++mt) acc[mt] = (f32x4){0.f, 0.f, 0.f, 0.f};
  f32x4 gacc[3];
#pragma unroll
  for (int j = 0; j < 3; ++j) gacc[j] = (f32x4){0.f, 0.f, 0.f, 0.f};

  for (int h = 0; h < 2; ++h) {
    const int db = h * 512;
    // stage ctx d-half: rows 0..35, coalesced f32 reads, 8B LDS writes
#pragma unroll
    for (int i = 0; i < 18; ++i) {
      int idx = t + 256 * i;
      int row = idx >> 7, c4 = (idx & 127) * 4;
      float4 v = *(const float4*)&context[((size_t)bb * SS + row) * DD + db + c4];
      ushort4 p;
      p.x = f2bf(v.x); p.y = f2bf(v.y); p.z = f2bf(v.z); p.w = f2bf(v.w);
      *(ushort4*)&ctxL[row * 520 + c4] = p;
    }
    __syncthreads();

    // barrier-free stream: 16 k-steps, manual 1-deep preload
    float4 qa = *(const float4*)(qrow + db);
    float4 qb = *(const float4*)(qrow + db + 4);
    float4 ma = *(const float4*)(mrow + db);
    float4 mb = *(const float4*)(mrow + db + 4);
#pragma unroll
    for (int ks = 0; ks < 16; ++ks) {
      u16x8 pk;
      pk[0] = f2bf(qa.x * ma.x); pk[1] = f2bf(qa.y * ma.y);
      pk[2] = f2bf(qa.z * ma.z); pk[3] = f2bf(qa.w * ma.w);
      pk[4] = f2bf(qb.x * mb.x); pk[5] = f2bf(qb.y * mb.y);
      pk[6] = f2bf(qb.z * mb.z); pk[7] = f2bf(qb.w * mb.w);
      if (ks < 15) {  // preload next step (consumer in same iter -> can't sink far)
        const float* q2 = qrow + db + (ks + 1) * 32;
        const float* m2 = mrow + db + (ks + 1) * 32;
        qa = *(const float4*)q2; qb = *(const float4*)(q2 + 4);
        ma = *(const float4*)m2; mb = *(const float4*)(m2 + 4);
      }
      bf16x8 bq = __builtin_bit_cast(bf16x8, pk);
      const int ko = ks * 32 + kg * 8;
      bf16x8 a0 = __builtin_bit_cast(bf16x8, *(const u16x8*)&ctxL[(0 + ml) * 520 + ko]);
      bf16x8 a1 = __builtin_bit_cast(bf16x8, *(const u16x8*)&ctxL[(16 + ml) * 520 + ko]);
      bf16x8 a2 = __builtin_bit_cast(bf16x8, *(const u16x8*)&ctxL[(32 + ml) * 520 + ko]);
      acc[0] = __builtin_amdgcn_mfma_f32_16x16x32_bf16(a0, bq, acc[0], 0, 0, 0);
      acc[1] = __builtin_amdgcn_mfma_f32_16x16x32_bf16(a1, bq, acc[1], 0, 0, 0);
      acc[2] = __builtin_amdgcn_mfma_f32_16x16x32_bf16(a2, bq, acc[2], 0, 0, 0);
    }

    // G contribution from this half (waves 0-2, LDS-only reads)
    if (w < 3) {
#pragma unroll
      for (int ks = 0; ks < 16; ++ks) {
        const int ko = ks * 32 + kg * 8;
        bf16x8 ai = __builtin_bit_cast(bf16x8, *(const u16x8*)&ctxL[(w * 16 + ml) * 520 + ko]);
#pragma unroll
        for (int j = 0; j < 3; ++j) {
          bf16x8 aj = __builtin_bit_cast(bf16x8, *(const u16x8*)&ctxL[(j * 16 + ml) * 520 + ko]);
          gacc[j] = __builtin_amdgcn_mfma_f32_16x16x32_bf16(ai, aj, gacc[j], 0, 0, 0);
        }
      }
    }
    __syncthreads();  // protect restage (h=0) / all-G-done (h=1)
  }

  // spill G bf16 to ws (rows/cols 36-47 are exact zeros)
  if (w < 3) {
#pragma unroll
    for (int j = 0; j < 3; ++j)
#pragma unroll
      for (int ii = 0; ii < 4; ++ii)
        Gws[(size_t)bb * 2304 + (w * 16 + kg * 4 + ii) * 48 + j * 16 + ml] = f2bf(gacc[j][ii]);
  }
  // leaky + spill scores to sc[s][q]
#pragma unroll
  for (int mt = 0; mt < 3; ++mt)
#pragma unroll
    for (int ii = 0; ii < 4; ++ii) {
      float v = acc[mt][ii];
      v = v > 0.f ? v : 0.1f * v;
      sc[(mt * 16 + kg * 4 + ii) * 68 + w * 16 + ml] = v;
    }
  __syncthreads();

  if (t < 36) {  // l2norm over q per row s
    float ssum = 0.f;
    for (int qi = 0; qi < 64; ++qi) { float v = sc[t * 68 + qi]; ssum = fmaf(v, v, ssum); }
    float rn = 1.f / (sqrtf(ssum) + 1e-8f);
    for (int qi = 0; qi < 64; ++qi) sc[t * 68 + qi] *= rn;
  }
  __syncthreads();

  if (t < 64) {  // softmax over s per column q -> probs bf16 to ws
    float mx = -1e30f;
    for (int s2 = 0; s2 < 36; ++s2) mx = fmaxf(mx, sc[s2 * 68 + t]);
    float sum = 0.f;
    float ev[36];
    for (int s2 = 0; s2 < 36; ++s2) {
      float e = __expf((sc[s2 * 68 + t] - mx) * smf);
      ev[s2] = e;
      sum += e;
    }
    float rs = 1.f / sum;
    size_t base = (size_t)bb * (QQ * SS) + t * SS;
#pragma unroll
    for (int s2 = 0; s2 < 36; s2 += 2) {
      ushort2 p;
      p.x = f2bf(ev[s2] * rs);
      p.y = f2bf(ev[s2 + 1] * rs);
      *(ushort2*)&attnBF[base + s2] = p;
    }
  }
}

// ---------------------------------------------------------------------------
// K2 (unchanged from R6): per-batch, 512 thr, 49.7KB LDS, chunk-order swizzle.
// ---------------------------------------------------------------------------
template <bool USE_W16>
__global__ __launch_bounds__(512, 4) void k2_fused(
    const float* __restrict__ query, const float* __restrict__ context,
    const float* __restrict__ Wm, const float* __restrict__ bvec,
    const us* __restrict__ attnBF, const us* __restrict__ Gws,
    const us* __restrict__ W16, float* __restrict__ out) {
  __shared__ __align__(16) char smem[49664];
  us* P16s = (us*)smem;                  // [64][72]
  us* ctxTs = (us*)(smem + 9216);        // [128][76], row stride 152B
  us* A16s = (us*)(smem + 28672);        // [64][136]
  us* Gf16L = (us*)(smem + 28672);       // [48][72] (aliases A16s, init only)
  float* biasL = (float*)(smem + 46080); // [256]
  float* rnL = (float*)(smem + 47104);   // [64]
  float* rsum = (float*)(smem + 47360);  // [64*9]

  const int t = threadIdx.x, bb = blockIdx.x;
  const int lane = t & 63, w = t >> 6;
  const int ml = lane & 15, kg = lane >> 4;
  const int chs = ((bb >> 3) ^ bb) & 7;  // chunk-order swizzle

  // ---- init: zero pads
  for (int idx = t; idx < 2304; idx += 512) ((unsigned*)P16s)[idx] = 0;
  for (int idx = t; idx < 1728; idx += 512) ((unsigned*)Gf16L)[idx] = 0;
  for (int idx = t; idx < 1792; idx += 512) {  // ctxT cols 36..63 zero (persist)
    int r = idx / 14, c = idx - r * 14;
    *(unsigned*)&ctxTs[r * 76 + 36 + c * 2] = 0;
  }
  if (t < 256) biasL[t] = bvec[t];
  __syncthreads();
  // fill P16 (bf16 copy) and Gf16L
  for (int idx = t; idx < 1152; idx += 512) {
    int q = idx / 18, c2 = idx - q * 18;
    *(unsigned*)&P16s[q * 72 + c2 * 2] = ((const unsigned*)attnBF)[(size_t)bb * 1152 + idx];
  }
  for (int idx = t; idx < 1152; idx += 512) {
    int r = idx / 24, c2 = idx - r * 24;
    *(unsigned*)&Gf16L[r * 72 + c2 * 2] = ((const unsigned*)Gws)[(size_t)bb * 1152 + idx];
  }
  __syncthreads();

  // ---- V = P.G^T (G symmetric), then ||wc_q||^2 = sum_sp p[q][sp]*V[q][sp]
  if (w < 3) {
    f32x4 accv[4];
#pragma unroll
    for (int mt = 0; mt < 4; ++mt) accv[mt] = (f32x4){0.f, 0.f, 0.f, 0.f};
#pragma unroll
    for (int ks = 0; ks < 2; ++ks) {
      const int ko = ks * 32 + kg * 8;
      bf16x8 gfr = __builtin_bit_cast(bf16x8, *(const u16x8*)&Gf16L[(w * 16 + ml) * 72 + ko]);
#pragma unroll
      for (int mt = 0; mt < 4; ++mt) {
        bf16x8 pf = __builtin_bit_cast(bf16x8, *(const u16x8*)&P16s[(mt * 16 + ml) * 72 + ko]);
        accv[mt] = __builtin_amdgcn_mfma_f32_16x16x32_bf16(pf, gfr, accv[mt], 0, 0, 0);
      }
    }
#pragma unroll
    for (int mt = 0; mt < 4; ++mt)
#pragma unroll
      for (int ii = 0; ii < 4; ++ii) {
        int q = mt * 16 + kg * 4 + ii;
        float vv = accv[mt][ii] * bf2f(P16s[q * 72 + w * 16 + ml]);
        vv += __shfl_xor(vv, 1);
        vv += __shfl_xor(vv, 2);
        vv += __shfl_xor(vv, 4);
        vv += __shfl_xor(vv, 8);
        if (ml == 0) rsum[q * 4 + w] = vv;
      }
  }
  __syncthreads();
  if (t < 64) {
    float s2 = rsum[t * 4] + rsum[t * 4 + 1] + rsum[t * 4 + 2];
    rnL[t] = 1.f / (sqrtf(s2) + 1e-8f);
  }

  // ---- main chunk loop
  f32x4 accs[4][2];
#pragma unroll
  for (int mt = 0; mt < 4; ++mt)
#pragma unroll
    for (int ntl = 0; ntl < 2; ++ntl) accs[mt][ntl] = (f32x4){0.f, 0.f, 0.f, 0.f};

  for (int ch = 0; ch < 8; ++ch) {
    const int d0 = ((ch + chs) & 7) * 128;
    // (a) stage ctxT: transposed global reads (coalesced rows), b64 LDS writes
    for (int idx = t; idx < 1152; idx += 512) {
      int d = idx & 127, s0 = (idx >> 7) * 4;
      const float* cp = &context[((size_t)bb * SS + s0) * DD + d0 + d];
      u16x4 pk;
      pk[0] = f2bf(cp[0]);
      pk[1] = f2bf(cp[DD]);
      pk[2] = f2bf(cp[2 * DD]);
      pk[3] = f2bf(cp[3 * DD]);
      *(u16x4*)&ctxTs[d * 76 + s0] = pk;
    }
    __syncthreads();  // (b)
    // (c) wc = P.C : wave w owns d-cols [w*16, w*16+16)
    f32x4 aw[4];
#pragma unroll
    for (int mt = 0; mt < 4; ++mt) aw[mt] = (f32x4){0.f, 0.f, 0.f, 0.f};
#pragma unroll
    for (int ks = 0; ks < 2; ++ks) {
      const int ko = ks * 32 + kg * 8;
      u16x4 blo = *(const u16x4*)&ctxTs[(w * 16 + ml) * 76 + ko];
      u16x4 bhi = *(const u16x4*)&ctxTs[(w * 16 + ml) * 76 + ko + 4];
      bf16x8 bfr = __builtin_bit_cast(bf16x8, __builtin_shufflevector(blo, bhi, 0, 1, 2, 3, 4, 5, 6, 7));
#pragma unroll
      for (int mt = 0; mt < 4; ++mt) {
        bf16x8 af = __builtin_bit_cast(bf16x8, *(const u16x8*)&P16s[(mt * 16 + ml) * 72 + ko]);
        aw[mt] = __builtin_amdgcn_mfma_f32_16x16x32_bf16(af, bfr, aw[mt], 0, 0, 0);
      }
    }
    // (d) A = (query - wc*rn)^2 -> A16 bf16
#pragma unroll
    for (int mt = 0; mt < 4; ++mt)
#pragma unroll
      for (int ii = 0; ii < 4; ++ii) {
        int q = mt * 16 + kg * 4 + ii;
        float qv = query[((size_t)bb * QQ + q) * DD + d0 + w * 16 + ml];
        float av = qv - aw[mt][ii] * rnL[q];
        A16s[q * 136 + w * 16 + ml] = f2bf(av * av);
      }
    __syncthreads();  // (e)
    // (f) sim GEMM: wave w owns out cols [w*32, w*32+32)
#pragma unroll
    for (int ks = 0; ks < 4; ++ks) {
      const int ko = ks * 32 + kg * 8;
      bf16x8 bfr[2];
#pragma unroll
      for (int ntl = 0; ntl < 2; ++ntl) {
        const size_t wrow = (size_t)(w * 32 + ntl * 16 + ml);
        if constexpr (USE_W16) {
          bfr[ntl] = __builtin_bit_cast(bf16x8, *(const u16x8*)&W16[wrow * DD + d0 + ko]);
        } else {
          const float4* wp = (const float4*)&Wm[wrow * DD + d0 + ko];
          float4 x = wp[0], y = wp[1];
          u16x8 pk;
          pk[0] = f2bf(x.x); pk[1] = f2bf(x.y); pk[2] = f2bf(x.z); pk[3] = f2bf(x.w);
          pk[4] = f2bf(y.x); pk[5] = f2bf(y.y); pk[6] = f2bf(y.z); pk[7] = f2bf(y.w);
          bfr[ntl] = __builtin_bit_cast(bf16x8, pk);
        }
      }
#pragma unroll
      for (int mt = 0; mt < 4; ++mt) {
        bf16x8 af = __builtin_bit_cast(bf16x8, *(const u16x8*)&A16s[(mt * 16 + ml) * 136 + ko]);
#pragma unroll
        for (int ntl = 0; ntl < 2; ++ntl)
          accs[mt][ntl] = __builtin_amdgcn_mfma_f32_16x16x32_bf16(af, bfr[ntl], accs[mt][ntl], 0, 0, 0);
      }
    }
    __syncthreads();  // (g)
  }

  // ---- epilogue: +bias, l2norm over 256, store
#pragma unroll
  for (int mt = 0; mt < 4; ++mt)
#pragma unroll
    for (int ii = 0; ii < 4; ++ii) {
      int q = mt * 16 + kg * 4 + ii;
      float partial = 0.f;
#pragma unroll
      for (int ntl = 0; ntl < 2; ++ntl) {
        int col = w * 32 + ntl * 16 + ml;
        float v = accs[mt][ntl][ii] + biasL[col];
        partial = fmaf(v, v, partial);
      }
      partial += __shfl_xor(partial, 1);
      partial += __shfl_xor(partial, 2);
      partial += __shfl_xor(partial, 4);
      partial += __shfl_xor(partial, 8);
      if (ml == 0) rsum[q * 9 + w] = partial;
    }
  __syncthreads();
  if (t < 64) {
    float ssum = 0.f;
#pragma unroll
    for (int w2 = 0; w2 < 8; ++w2) ssum += rsum[t * 9 + w2];
    rnL[t] = 1.f / (sqrtf(ssum) + 1e-8f);
  }
  __syncthreads();
#pragma unroll
  for (int mt = 0; mt < 4; ++mt)
#pragma unroll
    for (int ntl = 0; ntl < 2; ++ntl)
#pragma unroll
      for (int ii = 0; ii < 4; ++ii) {
        int q = mt * 16 + kg * 4 + ii;
        int col = w * 32 + ntl * 16 + ml;
        float v = accs[mt][ntl][ii] + biasL[col];
        out[((size_t)bb * QQ + q) * SIM + col] = v * rnL[q];
      }
}

extern "C" void kernel_launch(void* const* d_in, const int* in_sizes, int n_in,
                              void* d_out, int out_size, void* d_ws, size_t ws_size,
                              hipStream_t stream) {
  const float* query = (const float*)d_in[0];
  const float* context = (const float*)d_in[1];
  const float* matrix = (const float*)d_in[2];
  const float* Wm = (const float*)d_in[3];
  const float* bvec = (const float*)d_in[4];
  const int* smoothp = (const int*)d_in[5];
  float* out = (float*)d_out;

  // ws layout: [attn bf16: 2359296][G bf16: 2359296][W16 optional: 524288]
  const size_t attnB = (size_t)BB * QQ * SS * 2;
  us* attnBF = (us*)d_ws;
  us* Gws = (us*)((char*)d_ws + attnB);
  us* W16 = (us*)((char*)d_ws + 2 * attnB);
  const bool useW16 = ws_size >= 2 * attnB + (size_t)SIM * DD * 2;

  k1_attn<<<dim3(BB), dim3(256), 0, stream>>>(query, context, matrix, smoothp, attnBF, Gws);
  if (useW16) {
    k0_w16<<<dim3(SIM * DD / 1024), dim3(256), 0, stream>>>(Wm, W16);
    k2_fused<true><<<dim3(BB), dim3(512), 0, stream>>>(query, context, Wm, bvec, attnBF, Gws, W16, out);
  } else {
    k2_fused<false><<<dim3(BB), dim3(512), 0, stream>>>(query, context, Wm, bvec, attnBF, Gws, W16, out);
  }
}

// Round 9
// 160.589 us; speedup vs baseline: 1.0844x; 1.0456x over previous
//
#include <hip/hip_runtime.h>
#include <hip/hip_bf16.h>

// Problem dims (fixed by reference): B=512, Q=64, S=36, D=1024, SIM=256
#define BB 512
#define QQ 64
#define SS 36
#define DD 1024
#define SIM 256

typedef unsigned short u16x8 __attribute__((ext_vector_type(8)));
typedef unsigned short u16x4 __attribute__((ext_vector_type(4)));
typedef __bf16 bf16x8 __attribute__((ext_vector_type(8)));
typedef float f32x4 __attribute__((ext_vector_type(4)));
typedef unsigned short us;

__device__ __forceinline__ us f2bf(float f) {
  unsigned u = __float_as_uint(f);
  u += 0x7FFFu + ((u >> 16) & 1u);   // round-to-nearest-even
  return (us)(u >> 16);
}
__device__ __forceinline__ float bf2f(us h) {
  return __uint_as_float(((unsigned)h) << 16);
}

// ---------------------------------------------------------------------------
// K0: one-shot W (256x1024 f32) -> bf16 row-major copy in ws. L2-resident.
// ---------------------------------------------------------------------------
__global__ __launch_bounds__(256) void k0_w16(const float* __restrict__ W,
                                              us* __restrict__ W16) {
  int i = blockIdx.x * 256 + threadIdx.x;  // 65536 float4s
  float4 v = ((const float4*)W)[i];
  ushort4 p;
  p.x = f2bf(v.x); p.y = f2bf(v.y); p.z = f2bf(v.z); p.w = f2bf(v.w);
  ((ushort4*)W16)[i] = p;
}

// ---------------------------------------------------------------------------
// K_FUSED: the whole problem in one kernel, one batch per block.
// grid=512, block=512 (8 waves), 63.2KB LDS, 2 blocks/CU.
//
// Phase A (scores+G, 8 chunks of 128 d):
//   all waves stage qm=q*m bf16 [64][136] and ctx bf16 [48][136] (rows>=36 zero)
//   waves 0-3: scores MFMA (wave w = q-cols w*16..+16, 3 m-tiles)
//   waves 4-6: G = ctx.ctx^T row-block (w-4)           wave 7: staging only
// Epilogue A: leaky -> sc[s][q] f32; l2norm(Q); softmax(S) -> P16 bf16 (LDS);
//             G -> Gf16 bf16 (LDS). No workspace round-trip.
// Bridge: V = P.G^T (MFMA, waves 0-2) -> rn_q = 1/(sqrt(p.V)+eps).
// Phase B (8 chunks of 128 d; query/ctx re-reads are L3-hot from phase A):
//   stage ctxT[128][76]; wc = P.C (MFMA); A=(q-wc*rn)^2 bf16; sim GEMM A.W^T.
// Epilogue B: +bias, l2norm(SIM), store out.
//
// LDS map (phase A | phase B alias):
//   [0,17408)      qmL us[64][136]     | ctxTs us[128][76]  [0,19456)
//   [17408,30464)  ctxL us[48][136]    | (ctxTs tail)
//   [30464,43520)  sc f32[48][68]      | A16s us[64][136]   [19456,36864)
//   [43520,52736)  P16s us[64][72]   (persistent)
//   [52736,59648)  Gf16 us[48][72]   (persistent)
//   [59648,60672)  biasL f32[256] | [60672,60928) rnL f32[64]
//   [60928,63232)  rsum f32[64*9]
// ---------------------------------------------------------------------------
template <bool USE_W16>
__global__ __launch_bounds__(512, 4) void k_fused(
    const float* __restrict__ query, const float* __restrict__ context,
    const float* __restrict__ matrix, const float* __restrict__ Wm,
    const float* __restrict__ bvec, const int* __restrict__ smoothp,
    const us* __restrict__ W16, float* __restrict__ out) {
  __shared__ __align__(16) char smem[63232];
  us* qmL = (us*)smem;                    // [64][136] (phase A)
  us* ctxL = (us*)(smem + 17408);         // [48][136] (phase A)
  float* sc = (float*)(smem + 30464);     // [48][68]
  us* ctxTs = (us*)smem;                  // [128][76] (phase B)
  us* A16s = (us*)(smem + 19456);         // [64][136] (phase B)
  us* P16s = (us*)(smem + 43520);         // [64][72]
  us* Gf16L = (us*)(smem + 52736);        // [48][72]
  float* biasL = (float*)(smem + 59648);  // [256]
  float* rnL = (float*)(smem + 60672);    // [64]
  float* rsum = (float*)(smem + 60928);   // [64*9]

  const int t = threadIdx.x, bb = blockIdx.x;
  const int lane = t & 63, w = t >> 6;
  const int ml = lane & 15, kg = lane >> 4;
  const float smf = (float)smoothp[0];

  // init: zero P16 / Gf16 pads (regions untouched by phase A), load bias
  for (int idx = t; idx < 2304; idx += 512) ((unsigned*)P16s)[idx] = 0;
  for (int idx = t; idx < 1728; idx += 512) ((unsigned*)Gf16L)[idx] = 0;
  if (t < 256) biasL[t] = bvec[t];

  // ================= Phase A: scores + G =================
  f32x4 acc[3], gacc[3];
#pragma unroll
  for (int j = 0; j < 3; ++j) {
    acc[j] = (f32x4){0.f, 0.f, 0.f, 0.f};
    gacc[j] = (f32x4){0.f, 0.f, 0.f, 0.f};
  }

  for (int ch = 0; ch < 8; ++ch) {
    const int d0 = ch * 128;
    // stage qm = query*matrix bf16 (1024 slots: row, 8 consecutive d)
#pragma unroll
    for (int i = 0; i < 2; ++i) {
      int idx = t + 512 * i;
      int row = idx >> 4, c8 = idx & 15;
      const float4* gq = (const float4*)&query[((size_t)bb * QQ + row) * DD + d0 + c8 * 8];
      const float4* gm = (const float4*)&matrix[((size_t)bb * QQ + row) * DD + d0 + c8 * 8];
      float4 a0 = gq[0], a1 = gq[1], m0 = gm[0], m1 = gm[1];
      u16x8 pk;
      pk[0] = f2bf(a0.x * m0.x); pk[1] = f2bf(a0.y * m0.y);
      pk[2] = f2bf(a0.z * m0.z); pk[3] = f2bf(a0.w * m0.w);
      pk[4] = f2bf(a1.x * m1.x); pk[5] = f2bf(a1.y * m1.y);
      pk[6] = f2bf(a1.z * m1.z); pk[7] = f2bf(a1.w * m1.w);
      *(u16x8*)&qmL[row * 136 + c8 * 8] = pk;
    }
    // stage ctx bf16: slots t (rows 0..31) and 512+t for t<256 (rows 32..47)
    {
      int row = t >> 4, c8 = t & 15;  // rows 0..31, all real
      const float4* gc = (const float4*)&context[((size_t)bb * SS + row) * DD + d0 + c8 * 8];
      float4 a0 = gc[0], a1 = gc[1];
      u16x8 pk;
      pk[0] = f2bf(a0.x); pk[1] = f2bf(a0.y); pk[2] = f2bf(a0.z); pk[3] = f2bf(a0.w);
      pk[4] = f2bf(a1.x); pk[5] = f2bf(a1.y); pk[6] = f2bf(a1.z); pk[7] = f2bf(a1.w);
      *(u16x8*)&ctxL[row * 136 + c8 * 8] = pk;
    }
    if (t < 256) {
      int row = 32 + (t >> 4), c8 = t & 15;  // rows 32..47
      u16x8 pk = (u16x8){0, 0, 0, 0, 0, 0, 0, 0};
      if (row < 36) {
        const float4* gc = (const float4*)&context[((size_t)bb * SS + row) * DD + d0 + c8 * 8];
        float4 a0 = gc[0], a1 = gc[1];
        pk[0] = f2bf(a0.x); pk[1] = f2bf(a0.y); pk[2] = f2bf(a0.z); pk[3] = f2bf(a0.w);
        pk[4] = f2bf(a1.x); pk[5] = f2bf(a1.y); pk[6] = f2bf(a1.z); pk[7] = f2bf(a1.w);
      }
      *(u16x8*)&ctxL[row * 136 + c8 * 8] = pk;
    }
    __syncthreads();
#pragma unroll
    for (int ks = 0; ks < 4; ++ks) {
      const int ko = ks * 32 + kg * 8;
      if (w < 4) {  // scores: wave w -> q-cols w*16..+16
        bf16x8 bq = __builtin_bit_cast(bf16x8, *(const u16x8*)&qmL[(w * 16 + ml) * 136 + ko]);
#pragma unroll
        for (int mt = 0; mt < 3; ++mt) {
          bf16x8 af = __builtin_bit_cast(bf16x8, *(const u16x8*)&ctxL[(mt * 16 + ml) * 136 + ko]);
          acc[mt] = __builtin_amdgcn_mfma_f32_16x16x32_bf16(af, bq, acc[mt], 0, 0, 0);
        }
      } else if (w < 7) {  // G row-block w-4
        bf16x8 ai = __builtin_bit_cast(bf16x8, *(const u16x8*)&ctxL[((w - 4) * 16 + ml) * 136 + ko]);
#pragma unroll
        for (int j = 0; j < 3; ++j) {
          bf16x8 aj = __builtin_bit_cast(bf16x8, *(const u16x8*)&ctxL[(j * 16 + ml) * 136 + ko]);
          gacc[j] = __builtin_amdgcn_mfma_f32_16x16x32_bf16(ai, aj, gacc[j], 0, 0, 0);
        }
      }
    }
    __syncthreads();
  }

  // epilogue A: leaky -> sc; G -> Gf16 (bf16)
  if (w < 4) {
#pragma unroll
    for (int mt = 0; mt < 3; ++mt)
#pragma unroll
      for (int ii = 0; ii < 4; ++ii) {
        float v = acc[mt][ii];
        v = v > 0.f ? v : 0.1f * v;
        sc[(mt * 16 + kg * 4 + ii) * 68 + w * 16 + ml] = v;
      }
  } else if (w < 7) {
#pragma unroll
    for (int j = 0; j < 3; ++j)
#pragma unroll
      for (int ii = 0; ii < 4; ++ii)
        Gf16L[((w - 4) * 16 + kg * 4 + ii) * 72 + j * 16 + ml] = f2bf(gacc[j][ii]);
  }
  __syncthreads();

  if (t < 36) {  // l2norm over q per row s
    float ssum = 0.f;
    for (int qi = 0; qi < 64; ++qi) { float v = sc[t * 68 + qi]; ssum = fmaf(v, v, ssum); }
    float rn = 1.f / (sqrtf(ssum) + 1e-8f);
    for (int qi = 0; qi < 64; ++qi) sc[t * 68 + qi] *= rn;
  }
  __syncthreads();

  if (t < 64) {  // softmax over s per column q -> P16 (bf16, in LDS)
    float mx = -1e30f;
    for (int s2 = 0; s2 < 36; ++s2) mx = fmaxf(mx, sc[s2 * 68 + t]);
    float sum = 0.f;
    float ev[36];
    for (int s2 = 0; s2 < 36; ++s2) {
      float e = __expf((sc[s2 * 68 + t] - mx) * smf);
      ev[s2] = e;
      sum += e;
    }
    float rs = 1.f / sum;
#pragma unroll
    for (int s2 = 0; s2 < 36; ++s2) P16s[t * 72 + s2] = f2bf(ev[s2] * rs);
  }
  __syncthreads();

  // ================= Bridge: V = P.G^T -> rn_q =================
  if (w < 3) {
    f32x4 accv[4];
#pragma unroll
    for (int mt = 0; mt < 4; ++mt) accv[mt] = (f32x4){0.f, 0.f, 0.f, 0.f};
#pragma unroll
    for (int ks = 0; ks < 2; ++ks) {
      const int ko = ks * 32 + kg * 8;
      bf16x8 gfr = __builtin_bit_cast(bf16x8, *(const u16x8*)&Gf16L[(w * 16 + ml) * 72 + ko]);
#pragma unroll
      for (int mt = 0; mt < 4; ++mt) {
        bf16x8 pf = __builtin_bit_cast(bf16x8, *(const u16x8*)&P16s[(mt * 16 + ml) * 72 + ko]);
        accv[mt] = __builtin_amdgcn_mfma_f32_16x16x32_bf16(pf, gfr, accv[mt], 0, 0, 0);
      }
    }
#pragma unroll
    for (int mt = 0; mt < 4; ++mt)
#pragma unroll
      for (int ii = 0; ii < 4; ++ii) {
        int q = mt * 16 + kg * 4 + ii;
        float vv = accv[mt][ii] * bf2f(P16s[q * 72 + w * 16 + ml]);
        vv += __shfl_xor(vv, 1);
        vv += __shfl_xor(vv, 2);
        vv += __shfl_xor(vv, 4);
        vv += __shfl_xor(vv, 8);
        if (ml == 0) rsum[q * 4 + w] = vv;
      }
  }
  __syncthreads();
  if (t < 64) {
    float s2 = rsum[t * 4] + rsum[t * 4 + 1] + rsum[t * 4 + 2];
    rnL[t] = 1.f / (sqrtf(s2) + 1e-8f);
  }
  // zero ctxT pad cols [36,64) once (phase A regions are dead now)
  for (int idx = t; idx < 1792; idx += 512) {
    int r = idx / 14, c = idx - r * 14;
    *(unsigned*)&ctxTs[r * 76 + 36 + c * 2] = 0;
  }
  __syncthreads();

  // ================= Phase B: wc -> A -> sim GEMM =================
  f32x4 accs[4][2];
#pragma unroll
  for (int mt = 0; mt < 4; ++mt)
#pragma unroll
    for (int ntl = 0; ntl < 2; ++ntl) accs[mt][ntl] = (f32x4){0.f, 0.f, 0.f, 0.f};

  for (int ch = 0; ch < 8; ++ch) {
    const int d0 = ch * 128;
    // (a) stage ctxT (transposed reads; ctx is L3-hot from phase A)
    for (int idx = t; idx < 1152; idx += 512) {
      int d = idx & 127, s0 = (idx >> 7) * 4;
      const float* cp = &context[((size_t)bb * SS + s0) * DD + d0 + d];
      u16x4 pk;
      pk[0] = f2bf(cp[0]);
      pk[1] = f2bf(cp[DD]);
      pk[2] = f2bf(cp[2 * DD]);
      pk[3] = f2bf(cp[3 * DD]);
      *(u16x4*)&ctxTs[d * 76 + s0] = pk;
    }
    __syncthreads();
    // (c) wc = P.C : wave w owns d-cols [w*16, w*16+16)
    f32x4 aw[4];
#pragma unroll
    for (int mt = 0; mt < 4; ++mt) aw[mt] = (f32x4){0.f, 0.f, 0.f, 0.f};
#pragma unroll
    for (int ks = 0; ks < 2; ++ks) {
      const int ko = ks * 32 + kg * 8;
      u16x4 blo = *(const u16x4*)&ctxTs[(w * 16 + ml) * 76 + ko];
      u16x4 bhi = *(const u16x4*)&ctxTs[(w * 16 + ml) * 76 + ko + 4];
      bf16x8 bfr = __builtin_bit_cast(bf16x8, __builtin_shufflevector(blo, bhi, 0, 1, 2, 3, 4, 5, 6, 7));
#pragma unroll
      for (int mt = 0; mt < 4; ++mt) {
        bf16x8 af = __builtin_bit_cast(bf16x8, *(const u16x8*)&P16s[(mt * 16 + ml) * 72 + ko]);
        aw[mt] = __builtin_amdgcn_mfma_f32_16x16x32_bf16(af, bfr, aw[mt], 0, 0, 0);
      }
    }
    // (d) A = (query - wc*rn)^2 -> A16 bf16 (query L3-hot from phase A)
#pragma unroll
    for (int mt = 0; mt < 4; ++mt)
#pragma unroll
      for (int ii = 0; ii < 4; ++ii) {
        int q = mt * 16 + kg * 4 + ii;
        float qv = query[((size_t)bb * QQ + q) * DD + d0 + w * 16 + ml];
        float av = qv - aw[mt][ii] * rnL[q];
        A16s[q * 136 + w * 16 + ml] = f2bf(av * av);
      }
    __syncthreads();
    // (f) sim GEMM: wave w owns out cols [w*32, w*32+32)
#pragma unroll
    for (int ks = 0; ks < 4; ++ks) {
      const int ko = ks * 32 + kg * 8;
      bf16x8 bfr[2];
#pragma unroll
      for (int ntl = 0; ntl < 2; ++ntl) {
        const size_t wrow = (size_t)(w * 32 + ntl * 16 + ml);
        if constexpr (USE_W16) {
          bfr[ntl] = __builtin_bit_cast(bf16x8, *(const u16x8*)&W16[wrow * DD + d0 + ko]);
        } else {
          const float4* wp = (const float4*)&Wm[wrow * DD + d0 + ko];
          float4 x = wp[0], y = wp[1];
          u16x8 pk;
          pk[0] = f2bf(x.x); pk[1] = f2bf(x.y); pk[2] = f2bf(x.z); pk[3] = f2bf(x.w);
          pk[4] = f2bf(y.x); pk[5] = f2bf(y.y); pk[6] = f2bf(y.z); pk[7] = f2bf(y.w);
          bfr[ntl] = __builtin_bit_cast(bf16x8, pk);
        }
      }
#pragma unroll
      for (int mt = 0; mt < 4; ++mt) {
        bf16x8 af = __builtin_bit_cast(bf16x8, *(const u16x8*)&A16s[(mt * 16 + ml) * 136 + ko]);
#pragma unroll
        for (int ntl = 0; ntl < 2; ++ntl)
          accs[mt][ntl] = __builtin_amdgcn_mfma_f32_16x16x32_bf16(af, bfr[ntl], accs[mt][ntl], 0, 0, 0);
      }
    }
    __syncthreads();
  }

  // ================= Epilogue B: +bias, l2norm(SIM), store =================
#pragma unroll
  for (int mt = 0; mt < 4; ++mt)
#pragma unroll
    for (int ii = 0; ii < 4; ++ii) {
      int q = mt * 16 + kg * 4 + ii;
      float partial = 0.f;
#pragma unroll
      for (int ntl = 0; ntl < 2; ++ntl) {
        int col = w * 32 + ntl * 16 + ml;
        float v = accs[mt][ntl][ii] + biasL[col];
        partial = fmaf(v, v, partial);
      }
      partial += __shfl_xor(partial, 1);
      partial += __shfl_xor(partial, 2);
      partial += __shfl_xor(partial, 4);
      partial += __shfl_xor(partial, 8);
      if (ml == 0) rsum[q * 9 + w] = partial;
    }
  __syncthreads();
  if (t < 64) {
    float ssum = 0.f;
#pragma unroll
    for (int w2 = 0; w2 < 8; ++w2) ssum += rsum[t * 9 + w2];
    rnL[t] = 1.f / (sqrtf(ssum) + 1e-8f);
  }
  __syncthreads();
#pragma unroll
  for (int mt = 0; mt < 4; ++mt)
#pragma unroll
    for (int ntl = 0; ntl < 2; ++ntl)
#pragma unroll
      for (int ii = 0; ii < 4; ++ii) {
        int q = mt * 16 + kg * 4 + ii;
        int col = w * 32 + ntl * 16 + ml;
        float v = accs[mt][ntl][ii] + biasL[col];
        out[((size_t)bb * QQ + q) * SIM + col] = v * rnL[q];
      }
}

extern "C" void kernel_launch(void* const* d_in, const int* in_sizes, int n_in,
                              void* d_out, int out_size, void* d_ws, size_t ws_size,
                              hipStream_t stream) {
  const float* query = (const float*)d_in[0];
  const float* context = (const float*)d_in[1];
  const float* matrix = (const float*)d_in[2];
  const float* Wm = (const float*)d_in[3];
  const float* bvec = (const float*)d_in[4];
  const int* smoothp = (const int*)d_in[5];
  float* out = (float*)d_out;

  // ws: only W16 (512 KB). No attn/G round-trip anymore.
  us* W16 = (us*)d_ws;
  const bool useW16 = ws_size >= (size_t)SIM * DD * 2;

  if (useW16) {
    k0_w16<<<dim3(SIM * DD / 1024), dim3(256), 0, stream>>>(Wm, W16);
    k_fused<true><<<dim3(BB), dim3(512), 0, stream>>>(query, context, matrix, Wm,
                                                      bvec, smoothp, W16, out);
  } else {
    k_fused<false><<<dim3(BB), dim3(512), 0, stream>>>(query, context, matrix, Wm,
                                                       bvec, smoothp, W16, out);
  }
}

// Round 10
// 151.162 us; speedup vs baseline: 1.1520x; 1.0624x over previous
//
#include <hip/hip_runtime.h>
#include <hip/hip_bf16.h>

// Problem dims (fixed by reference): B=512, Q=64, S=36, D=1024, SIM=256
#define BB 512
#define QQ 64
#define SS 36
#define DD 1024
#define SIM 256

typedef unsigned short u16x8 __attribute__((ext_vector_type(8)));
typedef __bf16 bf16x8 __attribute__((ext_vector_type(8)));
typedef float f32x4 __attribute__((ext_vector_type(4)));
typedef unsigned short us;

__device__ __forceinline__ us f2bf(float f) {
  unsigned u = __float_as_uint(f);
  u += 0x7FFFu + ((u >> 16) & 1u);   // round-to-nearest-even
  return (us)(u >> 16);
}
__device__ __forceinline__ float bf2f(us h) {
  return __uint_as_float(((unsigned)h) << 16);
}

// ---------------------------------------------------------------------------
// K0: one-shot W (256x1024 f32) -> bf16 row-major copy in ws. L2-resident.
// ---------------------------------------------------------------------------
__global__ __launch_bounds__(256) void k0_w16(const float* __restrict__ W,
                                              us* __restrict__ W16) {
  int i = blockIdx.x * 256 + threadIdx.x;  // 65536 float4s
  float4 v = ((const float4*)W)[i];
  ushort4 p;
  p.x = f2bf(v.x); p.y = f2bf(v.y); p.z = f2bf(v.z); p.w = f2bf(v.w);
  ((ushort4*)W16)[i] = p;
}

// ---------------------------------------------------------------------------
// K_FUSED v2: one batch per block, 512 thr (8 waves), 150KB dynamic LDS,
// 1 block/CU. Context lives in LDS full-D for the WHOLE kernel -> phase B
// re-reads only query (staged coalesced into qB); ctx re-read + transposed
// global reads are gone. L2-side bytes 552 -> 477 MB.
//
// LDS map (byte offsets):
//   [0,99072)        ctxL us[48][1032]  full-D ctx bf16 (rows 36-47 zero)
//   [99072,116480)   X: qmL us[64][136] (A) | sc f32[48][68] | A16s (B)
//   [116480,133888)  qB us[64][136]     query chunk bf16 (phase B)
//   [133888,143104)  P16s us[64][72]
//   [143104,150016)  Gf16 us[48][72]
//   [150016,151040)  biasL f32[256]
//   [151040,151296)  rnL f32[64]
//   [151296,153600)  rsum f32[576]
// ---------------------------------------------------------------------------
#define KF_LDS 153600

template <bool USE_W16>
__global__ __launch_bounds__(512, 2) void k_fused(
    const float* __restrict__ query, const float* __restrict__ context,
    const float* __restrict__ matrix, const float* __restrict__ Wm,
    const float* __restrict__ bvec, const int* __restrict__ smoothp,
    const us* __restrict__ W16, float* __restrict__ out) {
  extern __shared__ __align__(16) char smem[];
  us* ctxL = (us*)smem;                    // [48][1032]
  us* qmL = (us*)(smem + 99072);           // [64][136] (phase A)
  float* sc = (float*)(smem + 99072);      // [48][68]  (bridge)
  us* A16s = (us*)(smem + 99072);          // [64][136] (phase B)
  us* qB = (us*)(smem + 116480);           // [64][136] (phase B)
  us* P16s = (us*)(smem + 133888);         // [64][72]
  us* Gf16L = (us*)(smem + 143104);        // [48][72]
  float* biasL = (float*)(smem + 150016);  // [256]
  float* rnL = (float*)(smem + 151040);    // [64]
  float* rsum = (float*)(smem + 151296);   // [576]

  const int t = threadIdx.x, bb = blockIdx.x;
  const int lane = t & 63, w = t >> 6;
  const int ml = lane & 15, kg = lane >> 4;
  const float smf = (float)smoothp[0];

  // init: zero ctxL rows 36-47, P16/Gf16 pads; load bias
  for (int idx = t; idx < 6192; idx += 512)
    ((unsigned*)(ctxL + 36 * 1032))[idx] = 0;
  for (int idx = t; idx < 2304; idx += 512) ((unsigned*)P16s)[idx] = 0;
  for (int idx = t; idx < 1728; idx += 512) ((unsigned*)Gf16L)[idx] = 0;
  if (t < 256) biasL[t] = bvec[t];

  // ================= Phase A: scores + G =================
  f32x4 acc[3], gacc[3];
#pragma unroll
  for (int j = 0; j < 3; ++j) {
    acc[j] = (f32x4){0.f, 0.f, 0.f, 0.f};
    gacc[j] = (f32x4){0.f, 0.f, 0.f, 0.f};
  }

  for (int ch = 0; ch < 8; ++ch) {
    const int d0 = ch * 128;
    // stage qm = query*matrix bf16 (chunked buffer)
#pragma unroll
    for (int i = 0; i < 2; ++i) {
      int idx = t + 512 * i;
      int row = idx >> 4, c8 = idx & 15;
      const float4* gq = (const float4*)&query[((size_t)bb * QQ + row) * DD + d0 + c8 * 8];
      const float4* gm = (const float4*)&matrix[((size_t)bb * QQ + row) * DD + d0 + c8 * 8];
      float4 a0 = gq[0], a1 = gq[1], m0 = gm[0], m1 = gm[1];
      u16x8 pk;
      pk[0] = f2bf(a0.x * m0.x); pk[1] = f2bf(a0.y * m0.y);
      pk[2] = f2bf(a0.z * m0.z); pk[3] = f2bf(a0.w * m0.w);
      pk[4] = f2bf(a1.x * m1.x); pk[5] = f2bf(a1.y * m1.y);
      pk[6] = f2bf(a1.z * m1.z); pk[7] = f2bf(a1.w * m1.w);
      *(u16x8*)&qmL[row * 136 + c8 * 8] = pk;
    }
    // stage ctx into FULL-D ctxL (rows 0..31 by all, 32..35 by t<64)
    {
      int row = t >> 4, c8 = t & 15;
      const float4* gc = (const float4*)&context[((size_t)bb * SS + row) * DD + d0 + c8 * 8];
      float4 a0 = gc[0], a1 = gc[1];
      u16x8 pk;
      pk[0] = f2bf(a0.x); pk[1] = f2bf(a0.y); pk[2] = f2bf(a0.z); pk[3] = f2bf(a0.w);
      pk[4] = f2bf(a1.x); pk[5] = f2bf(a1.y); pk[6] = f2bf(a1.z); pk[7] = f2bf(a1.w);
      *(u16x8*)&ctxL[row * 1032 + d0 + c8 * 8] = pk;
    }
    if (t < 64) {
      int row = 32 + (t >> 4), c8 = t & 15;
      const float4* gc = (const float4*)&context[((size_t)bb * SS + row) * DD + d0 + c8 * 8];
      float4 a0 = gc[0], a1 = gc[1];
      u16x8 pk;
      pk[0] = f2bf(a0.x); pk[1] = f2bf(a0.y); pk[2] = f2bf(a0.z); pk[3] = f2bf(a0.w);
      pk[4] = f2bf(a1.x); pk[5] = f2bf(a1.y); pk[6] = f2bf(a1.z); pk[7] = f2bf(a1.w);
      *(u16x8*)&ctxL[row * 1032 + d0 + c8 * 8] = pk;
    }
    __syncthreads();
#pragma unroll
    for (int ks = 0; ks < 4; ++ks) {
      const int ko = ks * 32 + kg * 8;
      if (w < 4) {  // scores: wave w -> q-cols w*16..+16
        bf16x8 bq = __builtin_bit_cast(bf16x8, *(const u16x8*)&qmL[(w * 16 + ml) * 136 + ko]);
#pragma unroll
        for (int mt = 0; mt < 3; ++mt) {
          bf16x8 af = __builtin_bit_cast(
              bf16x8, *(const u16x8*)&ctxL[(mt * 16 + ml) * 1032 + d0 + ko]);
          acc[mt] = __builtin_amdgcn_mfma_f32_16x16x32_bf16(af, bq, acc[mt], 0, 0, 0);
        }
      } else if (w < 7) {  // G row-block w-4
        bf16x8 ai = __builtin_bit_cast(
            bf16x8, *(const u16x8*)&ctxL[((w - 4) * 16 + ml) * 1032 + d0 + ko]);
#pragma unroll
        for (int j = 0; j < 3; ++j) {
          bf16x8 aj = __builtin_bit_cast(
              bf16x8, *(const u16x8*)&ctxL[(j * 16 + ml) * 1032 + d0 + ko]);
          gacc[j] = __builtin_amdgcn_mfma_f32_16x16x32_bf16(ai, aj, gacc[j], 0, 0, 0);
        }
      }
    }
    __syncthreads();
  }

  // epilogue A: leaky -> sc (aliases qmL); G -> Gf16
  if (w < 4) {
#pragma unroll
    for (int mt = 0; mt < 3; ++mt)
#pragma unroll
      for (int ii = 0; ii < 4; ++ii) {
        float v = acc[mt][ii];
        v = v > 0.f ? v : 0.1f * v;
        sc[(mt * 16 + kg * 4 + ii) * 68 + w * 16 + ml] = v;
      }
  } else if (w < 7) {
#pragma unroll
    for (int j = 0; j < 3; ++j)
#pragma unroll
      for (int ii = 0; ii < 4; ++ii)
        Gf16L[((w - 4) * 16 + kg * 4 + ii) * 72 + j * 16 + ml] = f2bf(gacc[j][ii]);
  }
  __syncthreads();

  if (t < 36) {  // l2norm over q per row s
    float ssum = 0.f;
    for (int qi = 0; qi < 64; ++qi) { float v = sc[t * 68 + qi]; ssum = fmaf(v, v, ssum); }
    float rn = 1.f / (sqrtf(ssum) + 1e-8f);
    for (int qi = 0; qi < 64; ++qi) sc[t * 68 + qi] *= rn;
  }
  __syncthreads();

  if (t < 64) {  // softmax over s per column q -> P16
    float mx = -1e30f;
    for (int s2 = 0; s2 < 36; ++s2) mx = fmaxf(mx, sc[s2 * 68 + t]);
    float sum = 0.f;
    float ev[36];
    for (int s2 = 0; s2 < 36; ++s2) {
      float e = __expf((sc[s2 * 68 + t] - mx) * smf);
      ev[s2] = e;
      sum += e;
    }
    float rs = 1.f / sum;
#pragma unroll
    for (int s2 = 0; s2 < 36; ++s2) P16s[t * 72 + s2] = f2bf(ev[s2] * rs);
  }
  __syncthreads();

  // ================= Bridge: V = P.G^T -> rn_q =================
  if (w < 3) {
    f32x4 accv[4];
#pragma unroll
    for (int mt = 0; mt < 4; ++mt) accv[mt] = (f32x4){0.f, 0.f, 0.f, 0.f};
#pragma unroll
    for (int ks = 0; ks < 2; ++ks) {
      const int ko = ks * 32 + kg * 8;
      bf16x8 gfr = __builtin_bit_cast(bf16x8, *(const u16x8*)&Gf16L[(w * 16 + ml) * 72 + ko]);
#pragma unroll
      for (int mt = 0; mt < 4; ++mt) {
        bf16x8 pf = __builtin_bit_cast(bf16x8, *(const u16x8*)&P16s[(mt * 16 + ml) * 72 + ko]);
        accv[mt] = __builtin_amdgcn_mfma_f32_16x16x32_bf16(pf, gfr, accv[mt], 0, 0, 0);
      }
    }
#pragma unroll
    for (int mt = 0; mt < 4; ++mt)
#pragma unroll
      for (int ii = 0; ii < 4; ++ii) {
        int q = mt * 16 + kg * 4 + ii;
        float vv = accv[mt][ii] * bf2f(P16s[q * 72 + w * 16 + ml]);
        vv += __shfl_xor(vv, 1);
        vv += __shfl_xor(vv, 2);
        vv += __shfl_xor(vv, 4);
        vv += __shfl_xor(vv, 8);
        if (ml == 0) rsum[q * 4 + w] = vv;
      }
  }
  __syncthreads();
  if (t < 64) {
    float s2 = rsum[t * 4] + rsum[t * 4 + 1] + rsum[t * 4 + 2];
    rnL[t] = 1.f / (sqrtf(s2) + 1e-8f);
  }
  __syncthreads();

  // ================= Phase B: qB -> wc -> A -> sim GEMM =================
  f32x4 accs[4][2];
#pragma unroll
  for (int mt = 0; mt < 4; ++mt)
#pragma unroll
    for (int ntl = 0; ntl < 2; ++ntl) accs[mt][ntl] = (f32x4){0.f, 0.f, 0.f, 0.f};

  for (int ch = 0; ch < 8; ++ch) {
    const int d0 = ch * 128;
    // (a) stage query chunk -> qB bf16 (coalesced, only global read here)
#pragma unroll
    for (int i = 0; i < 2; ++i) {
      int idx = t + 512 * i;
      int row = idx >> 4, c8 = idx & 15;
      const float4* gq = (const float4*)&query[((size_t)bb * QQ + row) * DD + d0 + c8 * 8];
      float4 a0 = gq[0], a1 = gq[1];
      u16x8 pk;
      pk[0] = f2bf(a0.x); pk[1] = f2bf(a0.y); pk[2] = f2bf(a0.z); pk[3] = f2bf(a0.w);
      pk[4] = f2bf(a1.x); pk[5] = f2bf(a1.y); pk[6] = f2bf(a1.z); pk[7] = f2bf(a1.w);
      *(u16x8*)&qB[row * 136 + c8 * 8] = pk;
    }
    // (c) wc = P.C : B-frags gathered from full-D ctxL (K = s, padded 64)
    f32x4 aw[4];
#pragma unroll
    for (int mt = 0; mt < 4; ++mt) aw[mt] = (f32x4){0.f, 0.f, 0.f, 0.f};
    {
      const int ncol = d0 + w * 16 + ml;
      u16x8 g0;
#pragma unroll
      for (int j = 0; j < 8; ++j) g0[j] = ctxL[(kg * 8 + j) * 1032 + ncol];
      bf16x8 bfr0 = __builtin_bit_cast(bf16x8, g0);
#pragma unroll
      for (int mt = 0; mt < 4; ++mt) {
        bf16x8 af = __builtin_bit_cast(bf16x8, *(const u16x8*)&P16s[(mt * 16 + ml) * 72 + kg * 8]);
        aw[mt] = __builtin_amdgcn_mfma_f32_16x16x32_bf16(af, bfr0, aw[mt], 0, 0, 0);
      }
      u16x8 g1;
#pragma unroll
      for (int j = 0; j < 8; ++j)
        g1[j] = (kg < 2) ? ctxL[(32 + kg * 8 + j) * 1032 + ncol] : (us)0;
      bf16x8 bfr1 = __builtin_bit_cast(bf16x8, g1);
#pragma unroll
      for (int mt = 0; mt < 4; ++mt) {
        bf16x8 af =
            __builtin_bit_cast(bf16x8, *(const u16x8*)&P16s[(mt * 16 + ml) * 72 + 32 + kg * 8]);
        aw[mt] = __builtin_amdgcn_mfma_f32_16x16x32_bf16(af, bfr1, aw[mt], 0, 0, 0);
      }
    }
    __syncthreads();  // qB ready; prev chunk's (f) reads of A16s done
    // (d) A = (q - wc*rn)^2 -> A16s bf16
#pragma unroll
    for (int mt = 0; mt < 4; ++mt)
#pragma unroll
      for (int ii = 0; ii < 4; ++ii) {
        int q = mt * 16 + kg * 4 + ii;
        float qv = bf2f(qB[q * 136 + w * 16 + ml]);
        float av = qv - aw[mt][ii] * rnL[q];
        A16s[q * 136 + w * 16 + ml] = f2bf(av * av);
      }
    __syncthreads();
    // (f) sim GEMM: wave w owns out cols [w*32, w*32+32)
#pragma unroll
    for (int ks = 0; ks < 4; ++ks) {
      const int ko = ks * 32 + kg * 8;
      bf16x8 bfr[2];
#pragma unroll
      for (int ntl = 0; ntl < 2; ++ntl) {
        const size_t wrow = (size_t)(w * 32 + ntl * 16 + ml);
        if constexpr (USE_W16) {
          bfr[ntl] = __builtin_bit_cast(bf16x8, *(const u16x8*)&W16[wrow * DD + d0 + ko]);
        } else {
          const float4* wp = (const float4*)&Wm[wrow * DD + d0 + ko];
          float4 x = wp[0], y = wp[1];
          u16x8 pk;
          pk[0] = f2bf(x.x); pk[1] = f2bf(x.y); pk[2] = f2bf(x.z); pk[3] = f2bf(x.w);
          pk[4] = f2bf(y.x); pk[5] = f2bf(y.y); pk[6] = f2bf(y.z); pk[7] = f2bf(y.w);
          bfr[ntl] = __builtin_bit_cast(bf16x8, pk);
        }
      }
#pragma unroll
      for (int mt = 0; mt < 4; ++mt) {
        bf16x8 af = __builtin_bit_cast(bf16x8, *(const u16x8*)&A16s[(mt * 16 + ml) * 136 + ko]);
#pragma unroll
        for (int ntl = 0; ntl < 2; ++ntl)
          accs[mt][ntl] =
              __builtin_amdgcn_mfma_f32_16x16x32_bf16(af, bfr[ntl], accs[mt][ntl], 0, 0, 0);
      }
    }
  }
  __syncthreads();

  // ================= Epilogue B: +bias, l2norm(SIM), store =================
#pragma unroll
  for (int mt = 0; mt < 4; ++mt)
#pragma unroll
    for (int ii = 0; ii < 4; ++ii) {
      int q = mt * 16 + kg * 4 + ii;
      float partial = 0.f;
#pragma unroll
      for (int ntl = 0; ntl < 2; ++ntl) {
        int col = w * 32 + ntl * 16 + ml;
        float v = accs[mt][ntl][ii] + biasL[col];
        partial = fmaf(v, v, partial);
      }
      partial += __shfl_xor(partial, 1);
      partial += __shfl_xor(partial, 2);
      partial += __shfl_xor(partial, 4);
      partial += __shfl_xor(partial, 8);
      if (ml == 0) rsum[q * 9 + w] = partial;
    }
  __syncthreads();
  if (t < 64) {
    float ssum = 0.f;
#pragma unroll
    for (int w2 = 0; w2 < 8; ++w2) ssum += rsum[t * 9 + w2];
    rnL[t] = 1.f / (sqrtf(ssum) + 1e-8f);
  }
  __syncthreads();
#pragma unroll
  for (int mt = 0; mt < 4; ++mt)
#pragma unroll
    for (int ntl = 0; ntl < 2; ++ntl)
#pragma unroll
      for (int ii = 0; ii < 4; ++ii) {
        int q = mt * 16 + kg * 4 + ii;
        int col = w * 32 + ntl * 16 + ml;
        float v = accs[mt][ntl][ii] + biasL[col];
        out[((size_t)bb * QQ + q) * SIM + col] = v * rnL[q];
      }
}

extern "C" void kernel_launch(void* const* d_in, const int* in_sizes, int n_in,
                              void* d_out, int out_size, void* d_ws, size_t ws_size,
                              hipStream_t stream) {
  const float* query = (const float*)d_in[0];
  const float* context = (const float*)d_in[1];
  const float* matrix = (const float*)d_in[2];
  const float* Wm = (const float*)d_in[3];
  const float* bvec = (const float*)d_in[4];
  const int* smoothp = (const int*)d_in[5];
  float* out = (float*)d_out;

  us* W16 = (us*)d_ws;
  const bool useW16 = ws_size >= (size_t)SIM * DD * 2;

  hipFuncSetAttribute((const void*)k_fused<true>,
                      hipFuncAttributeMaxDynamicSharedMemorySize, KF_LDS);
  hipFuncSetAttribute((const void*)k_fused<false>,
                      hipFuncAttributeMaxDynamicSharedMemorySize, KF_LDS);

  if (useW16) {
    k0_w16<<<dim3(SIM * DD / 1024), dim3(256), 0, stream>>>(Wm, W16);
    k_fused<true><<<dim3(BB), dim3(512), KF_LDS, stream>>>(query, context, matrix, Wm,
                                                           bvec, smoothp, W16, out);
  } else {
    k_fused<false><<<dim3(BB), dim3(512), KF_LDS, stream>>>(query, context, matrix, Wm,
                                                            bvec, smoothp, W16, out);
  }
}

// Round 11
// 142.432 us; speedup vs baseline: 1.2226x; 1.0613x over previous
//
#include <hip/hip_runtime.h>
#include <hip/hip_bf16.h>

// Problem dims (fixed by reference): B=512, Q=64, S=36, D=1024, SIM=256
#define BB 512
#define QQ 64
#define SS 36
#define DD 1024
#define SIM 256

typedef unsigned short u16x8 __attribute__((ext_vector_type(8)));
typedef __bf16 bf16x8 __attribute__((ext_vector_type(8)));
typedef float f32x4 __attribute__((ext_vector_type(4)));
typedef unsigned short us;

__device__ __forceinline__ us f2bf(float f) {
  unsigned u = __float_as_uint(f);
  u += 0x7FFFu + ((u >> 16) & 1u);   // round-to-nearest-even
  return (us)(u >> 16);
}
__device__ __forceinline__ float bf2f(us h) {
  return __uint_as_float(((unsigned)h) << 16);
}

// ---------------------------------------------------------------------------
// K0: one-shot W (256x1024 f32) -> bf16 row-major copy in ws. L2-resident.
// ---------------------------------------------------------------------------
__global__ __launch_bounds__(256) void k0_w16(const float* __restrict__ W,
                                              us* __restrict__ W16) {
  int i = blockIdx.x * 256 + threadIdx.x;  // 65536 float4s
  float4 v = ((const float4*)W)[i];
  ushort4 p;
  p.x = f2bf(v.x); p.y = f2bf(v.y); p.z = f2bf(v.z); p.w = f2bf(v.w);
  ((ushort4*)W16)[i] = p;
}

// ---------------------------------------------------------------------------
// K_FUSED v3: one batch per block, 512 thr (8 waves), 136.2KB dyn LDS,
// 1 block/CU. NEW vs v2: each thread stashes its phase-B query fragment
// slice in registers during phase A (16 bf16 x 8 chunks = 64 VGPR), loaded
// L2-hot right after staging the same chunk. Phase B reads NO input globals
// (only W16, L2-resident 512KB). L2/L3-side bytes 510 -> 377 MB (= input
// + output floor). Both chunk loops unrolled so stash indices are static.
//
// LDS map (byte offsets):
//   [0,99072)        ctxL us[48][1032]  full-D ctx bf16 (rows 36-47 zero)
//   [99072,116480)   X: qmL us[64][136] (A) | sc f32[48][68] | A16s (B)
//   [116480,125696)  P16s us[64][72]
//   [125696,132608)  Gf16 us[48][72]
//   [132608,133632)  biasL f32[256]
//   [133632,133888)  rnL f32[64]
//   [133888,136192)  rsum f32[576]
// ---------------------------------------------------------------------------
#define KF_LDS 136192

template <bool USE_W16>
__global__ __launch_bounds__(512, 2) void k_fused(
    const float* __restrict__ query, const float* __restrict__ context,
    const float* __restrict__ matrix, const float* __restrict__ Wm,
    const float* __restrict__ bvec, const int* __restrict__ smoothp,
    const us* __restrict__ W16, float* __restrict__ out) {
  extern __shared__ __align__(16) char smem[];
  us* ctxL = (us*)smem;                    // [48][1032]
  us* qmL = (us*)(smem + 99072);           // [64][136] (phase A)
  float* sc = (float*)(smem + 99072);      // [48][68]  (bridge)
  us* A16s = (us*)(smem + 99072);          // [64][136] (phase B)
  us* P16s = (us*)(smem + 116480);         // [64][72]
  us* Gf16L = (us*)(smem + 125696);        // [48][72]
  float* biasL = (float*)(smem + 132608);  // [256]
  float* rnL = (float*)(smem + 133632);    // [64]
  float* rsum = (float*)(smem + 133888);   // [576]

  const int t = threadIdx.x, bb = blockIdx.x;
  const int lane = t & 63, w = t >> 6;
  const int ml = lane & 15, kg = lane >> 4;
  const float smf = (float)smoothp[0];

  // init: zero ctxL rows 36-47, P16/Gf16 pads; load bias
  for (int idx = t; idx < 6192; idx += 512)
    ((unsigned*)(ctxL + 36 * 1032))[idx] = 0;
  for (int idx = t; idx < 2304; idx += 512) ((unsigned*)P16s)[idx] = 0;
  for (int idx = t; idx < 1728; idx += 512) ((unsigned*)Gf16L)[idx] = 0;
  if (t < 256) biasL[t] = bvec[t];

  // register stash of this thread's phase-B query slice:
  // element e=mt*4+ii of chunk ch is query[bb][mt*16+kg*4+ii][ch*128+w*16+ml]
  u16x8 qr0[8], qr1[8];  // e<8 (mt 0,1) | e>=8 (mt 2,3)

  // ================= Phase A: scores + G (+query stash) =================
  f32x4 acc[3], gacc[3];
#pragma unroll
  for (int j = 0; j < 3; ++j) {
    acc[j] = (f32x4){0.f, 0.f, 0.f, 0.f};
    gacc[j] = (f32x4){0.f, 0.f, 0.f, 0.f};
  }

#pragma unroll
  for (int ch = 0; ch < 8; ++ch) {
    const int d0 = ch * 128;
    // stage qm = query*matrix bf16
#pragma unroll
    for (int i = 0; i < 2; ++i) {
      int idx = t + 512 * i;
      int row = idx >> 4, c8 = idx & 15;
      const float4* gq = (const float4*)&query[((size_t)bb * QQ + row) * DD + d0 + c8 * 8];
      const float4* gm = (const float4*)&matrix[((size_t)bb * QQ + row) * DD + d0 + c8 * 8];
      float4 a0 = gq[0], a1 = gq[1], m0 = gm[0], m1 = gm[1];
      u16x8 pk;
      pk[0] = f2bf(a0.x * m0.x); pk[1] = f2bf(a0.y * m0.y);
      pk[2] = f2bf(a0.z * m0.z); pk[3] = f2bf(a0.w * m0.w);
      pk[4] = f2bf(a1.x * m1.x); pk[5] = f2bf(a1.y * m1.y);
      pk[6] = f2bf(a1.z * m1.z); pk[7] = f2bf(a1.w * m1.w);
      *(u16x8*)&qmL[row * 136 + c8 * 8] = pk;
    }
    // stage ctx into FULL-D ctxL (rows 0..31 by all, 32..35 by t<64)
    {
      int row = t >> 4, c8 = t & 15;
      const float4* gc = (const float4*)&context[((size_t)bb * SS + row) * DD + d0 + c8 * 8];
      float4 a0 = gc[0], a1 = gc[1];
      u16x8 pk;
      pk[0] = f2bf(a0.x); pk[1] = f2bf(a0.y); pk[2] = f2bf(a0.z); pk[3] = f2bf(a0.w);
      pk[4] = f2bf(a1.x); pk[5] = f2bf(a1.y); pk[6] = f2bf(a1.z); pk[7] = f2bf(a1.w);
      *(u16x8*)&ctxL[row * 1032 + d0 + c8 * 8] = pk;
    }
    if (t < 64) {
      int row = 32 + (t >> 4), c8 = t & 15;
      const float4* gc = (const float4*)&context[((size_t)bb * SS + row) * DD + d0 + c8 * 8];
      float4 a0 = gc[0], a1 = gc[1];
      u16x8 pk;
      pk[0] = f2bf(a0.x); pk[1] = f2bf(a0.y); pk[2] = f2bf(a0.z); pk[3] = f2bf(a0.w);
      pk[4] = f2bf(a1.x); pk[5] = f2bf(a1.y); pk[6] = f2bf(a1.z); pk[7] = f2bf(a1.w);
      *(u16x8*)&ctxL[row * 1032 + d0 + c8 * 8] = pk;
    }
    // issue query-stash loads (L2-hot: same chunk just staged above);
    // latency hides under the barrier + MFMA phase.
    float sv[16];
    {
      const float* qcol = query + (size_t)bb * QQ * DD + d0 + w * 16 + ml;
#pragma unroll
      for (int j = 0; j < 16; ++j) {
        int q = (j >> 2) * 16 + kg * 4 + (j & 3);
        sv[j] = qcol[(size_t)q * DD];
      }
    }
    __syncthreads();
#pragma unroll
    for (int ks = 0; ks < 4; ++ks) {
      const int ko = ks * 32 + kg * 8;
      if (w < 4) {  // scores: wave w -> q-cols w*16..+16
        bf16x8 bq = __builtin_bit_cast(bf16x8, *(const u16x8*)&qmL[(w * 16 + ml) * 136 + ko]);
#pragma unroll
        for (int mt = 0; mt < 3; ++mt) {
          bf16x8 af = __builtin_bit_cast(
              bf16x8, *(const u16x8*)&ctxL[(mt * 16 + ml) * 1032 + d0 + ko]);
          acc[mt] = __builtin_amdgcn_mfma_f32_16x16x32_bf16(af, bq, acc[mt], 0, 0, 0);
        }
      } else if (w < 7) {  // G row-block w-4
        bf16x8 ai = __builtin_bit_cast(
            bf16x8, *(const u16x8*)&ctxL[((w - 4) * 16 + ml) * 1032 + d0 + ko]);
#pragma unroll
        for (int j = 0; j < 3; ++j) {
          bf16x8 aj = __builtin_bit_cast(
              bf16x8, *(const u16x8*)&ctxL[(j * 16 + ml) * 1032 + d0 + ko]);
          gacc[j] = __builtin_amdgcn_mfma_f32_16x16x32_bf16(ai, aj, gacc[j], 0, 0, 0);
        }
      }
    }
    // pack stash for this chunk (static indices -> stays in VGPRs)
    {
      u16x8 s0, s1;
#pragma unroll
      for (int j = 0; j < 8; ++j) {
        s0[j] = f2bf(sv[j]);
        s1[j] = f2bf(sv[8 + j]);
      }
      qr0[ch] = s0;
      qr1[ch] = s1;
    }
    __syncthreads();
  }

  // epilogue A: leaky -> sc (aliases qmL); G -> Gf16
  if (w < 4) {
#pragma unroll
    for (int mt = 0; mt < 3; ++mt)
#pragma unroll
      for (int ii = 0; ii < 4; ++ii) {
        float v = acc[mt][ii];
        v = v > 0.f ? v : 0.1f * v;
        sc[(mt * 16 + kg * 4 + ii) * 68 + w * 16 + ml] = v;
      }
  } else if (w < 7) {
#pragma unroll
    for (int j = 0; j < 3; ++j)
#pragma unroll
      for (int ii = 0; ii < 4; ++ii)
        Gf16L[((w - 4) * 16 + kg * 4 + ii) * 72 + j * 16 + ml] = f2bf(gacc[j][ii]);
  }
  __syncthreads();

  if (t < 36) {  // l2norm over q per row s
    float ssum = 0.f;
    for (int qi = 0; qi < 64; ++qi) { float v = sc[t * 68 + qi]; ssum = fmaf(v, v, ssum); }
    float rn = 1.f / (sqrtf(ssum) + 1e-8f);
    for (int qi = 0; qi < 64; ++qi) sc[t * 68 + qi] *= rn;
  }
  __syncthreads();

  if (t < 64) {  // softmax over s per column q -> P16
    float mx = -1e30f;
    for (int s2 = 0; s2 < 36; ++s2) mx = fmaxf(mx, sc[s2 * 68 + t]);
    float sum = 0.f;
    float ev[36];
    for (int s2 = 0; s2 < 36; ++s2) {
      float e = __expf((sc[s2 * 68 + t] - mx) * smf);
      ev[s2] = e;
      sum += e;
    }
    float rs = 1.f / sum;
#pragma unroll
    for (int s2 = 0; s2 < 36; ++s2) P16s[t * 72 + s2] = f2bf(ev[s2] * rs);
  }
  __syncthreads();

  // ================= Bridge: V = P.G^T -> rn_q =================
  if (w < 3) {
    f32x4 accv[4];
#pragma unroll
    for (int mt = 0; mt < 4; ++mt) accv[mt] = (f32x4){0.f, 0.f, 0.f, 0.f};
#pragma unroll
    for (int ks = 0; ks < 2; ++ks) {
      const int ko = ks * 32 + kg * 8;
      bf16x8 gfr = __builtin_bit_cast(bf16x8, *(const u16x8*)&Gf16L[(w * 16 + ml) * 72 + ko]);
#pragma unroll
      for (int mt = 0; mt < 4; ++mt) {
        bf16x8 pf = __builtin_bit_cast(bf16x8, *(const u16x8*)&P16s[(mt * 16 + ml) * 72 + ko]);
        accv[mt] = __builtin_amdgcn_mfma_f32_16x16x32_bf16(pf, gfr, accv[mt], 0, 0, 0);
      }
    }
#pragma unroll
    for (int mt = 0; mt < 4; ++mt)
#pragma unroll
      for (int ii = 0; ii < 4; ++ii) {
        int q = mt * 16 + kg * 4 + ii;
        float vv = accv[mt][ii] * bf2f(P16s[q * 72 + w * 16 + ml]);
        vv += __shfl_xor(vv, 1);
        vv += __shfl_xor(vv, 2);
        vv += __shfl_xor(vv, 4);
        vv += __shfl_xor(vv, 8);
        if (ml == 0) rsum[q * 4 + w] = vv;
      }
  }
  __syncthreads();
  if (t < 64) {
    float s2 = rsum[t * 4] + rsum[t * 4 + 1] + rsum[t * 4 + 2];
    rnL[t] = 1.f / (sqrtf(s2) + 1e-8f);
  }
  __syncthreads();

  // ================= Phase B: wc -> A -> sim GEMM (no input globals) ======
  f32x4 accs[4][2];
#pragma unroll
  for (int mt = 0; mt < 4; ++mt)
#pragma unroll
    for (int ntl = 0; ntl < 2; ++ntl) accs[mt][ntl] = (f32x4){0.f, 0.f, 0.f, 0.f};

#pragma unroll
  for (int ch = 0; ch < 8; ++ch) {
    const int d0 = ch * 128;
    // (c) wc = P.C : B-frags gathered from full-D ctxL (K = s, padded 64)
    f32x4 aw[4];
#pragma unroll
    for (int mt = 0; mt < 4; ++mt) aw[mt] = (f32x4){0.f, 0.f, 0.f, 0.f};
    {
      const int ncol = d0 + w * 16 + ml;
      u16x8 g0;
#pragma unroll
      for (int j = 0; j < 8; ++j) g0[j] = ctxL[(kg * 8 + j) * 1032 + ncol];
      bf16x8 bfr0 = __builtin_bit_cast(bf16x8, g0);
#pragma unroll
      for (int mt = 0; mt < 4; ++mt) {
        bf16x8 af = __builtin_bit_cast(bf16x8, *(const u16x8*)&P16s[(mt * 16 + ml) * 72 + kg * 8]);
        aw[mt] = __builtin_amdgcn_mfma_f32_16x16x32_bf16(af, bfr0, aw[mt], 0, 0, 0);
      }
      u16x8 g1;
#pragma unroll
      for (int j = 0; j < 8; ++j)
        g1[j] = (kg < 2) ? ctxL[(32 + kg * 8 + j) * 1032 + ncol] : (us)0;
      bf16x8 bfr1 = __builtin_bit_cast(bf16x8, g1);
#pragma unroll
      for (int mt = 0; mt < 4; ++mt) {
        bf16x8 af =
            __builtin_bit_cast(bf16x8, *(const u16x8*)&P16s[(mt * 16 + ml) * 72 + 32 + kg * 8]);
        aw[mt] = __builtin_amdgcn_mfma_f32_16x16x32_bf16(af, bfr1, aw[mt], 0, 0, 0);
      }
    }
    __syncthreads();  // prev chunk's (f) reads of A16s done
    // (d) A = (q - wc*rn)^2 -> A16s bf16, query from register stash
#pragma unroll
    for (int mt = 0; mt < 4; ++mt)
#pragma unroll
      for (int ii = 0; ii < 4; ++ii) {
        int q = mt * 16 + kg * 4 + ii;
        const int e = mt * 4 + ii;
        float qv = bf2f(e < 8 ? qr0[ch][e] : qr1[ch][e - 8]);
        float av = qv - aw[mt][ii] * rnL[q];
        A16s[q * 136 + w * 16 + ml] = f2bf(av * av);
      }
    __syncthreads();
    // (f) sim GEMM: wave w owns out cols [w*32, w*32+32)
#pragma unroll
    for (int ks = 0; ks < 4; ++ks) {
      const int ko = ks * 32 + kg * 8;
      bf16x8 bfr[2];
#pragma unroll
      for (int ntl = 0; ntl < 2; ++ntl) {
        const size_t wrow = (size_t)(w * 32 + ntl * 16 + ml);
        if constexpr (USE_W16) {
          bfr[ntl] = __builtin_bit_cast(bf16x8, *(const u16x8*)&W16[wrow * DD + d0 + ko]);
        } else {
          const float4* wp = (const float4*)&Wm[wrow * DD + d0 + ko];
          float4 x = wp[0], y = wp[1];
          u16x8 pk;
          pk[0] = f2bf(x.x); pk[1] = f2bf(x.y); pk[2] = f2bf(x.z); pk[3] = f2bf(x.w);
          pk[4] = f2bf(y.x); pk[5] = f2bf(y.y); pk[6] = f2bf(y.z); pk[7] = f2bf(y.w);
          bfr[ntl] = __builtin_bit_cast(bf16x8, pk);
        }
      }
#pragma unroll
      for (int mt = 0; mt < 4; ++mt) {
        bf16x8 af = __builtin_bit_cast(bf16x8, *(const u16x8*)&A16s[(mt * 16 + ml) * 136 + ko]);
#pragma unroll
        for (int ntl = 0; ntl < 2; ++ntl)
          accs[mt][ntl] =
              __builtin_amdgcn_mfma_f32_16x16x32_bf16(af, bfr[ntl], accs[mt][ntl], 0, 0, 0);
      }
    }
  }
  __syncthreads();

  // ================= Epilogue B: +bias, l2norm(SIM), store =================
#pragma unroll
  for (int mt = 0; mt < 4; ++mt)
#pragma unroll
    for (int ii = 0; ii < 4; ++ii) {
      int q = mt * 16 + kg * 4 + ii;
      float partial = 0.f;
#pragma unroll
      for (int ntl = 0; ntl < 2; ++ntl) {
        int col = w * 32 + ntl * 16 + ml;
        float v = accs[mt][ntl][ii] + biasL[col];
        partial = fmaf(v, v, partial);
      }
      partial += __shfl_xor(partial, 1);
      partial += __shfl_xor(partial, 2);
      partial += __shfl_xor(partial, 4);
      partial += __shfl_xor(partial, 8);
      if (ml == 0) rsum[q * 9 + w] = partial;
    }
  __syncthreads();
  if (t < 64) {
    float ssum = 0.f;
#pragma unroll
    for (int w2 = 0; w2 < 8; ++w2) ssum += rsum[t * 9 + w2];
    rnL[t] = 1.f / (sqrtf(ssum) + 1e-8f);
  }
  __syncthreads();
#pragma unroll
  for (int mt = 0; mt < 4; ++mt)
#pragma unroll
    for (int ntl = 0; ntl < 2; ++ntl)
#pragma unroll
      for (int ii = 0; ii < 4; ++ii) {
        int q = mt * 16 + kg * 4 + ii;
        int col = w * 32 + ntl * 16 + ml;
        float v = accs[mt][ntl][ii] + biasL[col];
        out[((size_t)bb * QQ + q) * SIM + col] = v * rnL[q];
      }
}

extern "C" void kernel_launch(void* const* d_in, const int* in_sizes, int n_in,
                              void* d_out, int out_size, void* d_ws, size_t ws_size,
                              hipStream_t stream) {
  const float* query = (const float*)d_in[0];
  const float* context = (const float*)d_in[1];
  const float* matrix = (const float*)d_in[2];
  const float* Wm = (const float*)d_in[3];
  const float* bvec = (const float*)d_in[4];
  const int* smoothp = (const int*)d_in[5];
  float* out = (float*)d_out;

  us* W16 = (us*)d_ws;
  const bool useW16 = ws_size >= (size_t)SIM * DD * 2;

  hipFuncSetAttribute((const void*)k_fused<true>,
                      hipFuncAttributeMaxDynamicSharedMemorySize, KF_LDS);
  hipFuncSetAttribute((const void*)k_fused<false>,
                      hipFuncAttributeMaxDynamicSharedMemorySize, KF_LDS);

  if (useW16) {
    k0_w16<<<dim3(SIM * DD / 1024), dim3(256), 0, stream>>>(Wm, W16);
    k_fused<true><<<dim3(BB), dim3(512), KF_LDS, stream>>>(query, context, matrix, Wm,
                                                           bvec, smoothp, W16, out);
  } else {
    k_fused<false><<<dim3(BB), dim3(512), KF_LDS, stream>>>(query, context, matrix, Wm,
                                                            bvec, smoothp, W16, out);
  }
}